// Round 13
// baseline (13143.823 us; speedup 1.0000x reference)
//
#include <hip/hip_runtime.h>
#include <hip/hip_bf16.h>

#define LSEQ 2048
#define NCH 32          // chunks per sequence
#define CHL 64          // chunk length (NCH*CHL == LSEQ)

typedef __attribute__((ext_vector_type(8))) short bf16x8;
typedef __attribute__((ext_vector_type(4))) float f32x4;
typedef __hip_bfloat16 bf16;

__device__ __forceinline__ void gload_lds16(const void* g, void* l) {
  __builtin_amdgcn_global_load_lds(
      (const __attribute__((address_space(1))) void*)g,
      (__attribute__((address_space(3))) void*)l, 16, 0, 0);
}

__device__ __forceinline__ void split_bf16(float v, bf16& h, bf16& l) {
  h = __float2bfloat16(v);
  l = __float2bfloat16(v - __bfloat162float(h));
}

// ---------------- embed (also clears scan flags for this call) ----------------
__global__ __launch_bounds__(256) void embed_kernel(const int* __restrict__ x,
                                                    const float* __restrict__ emb,
                                                    float* __restrict__ h,
                                                    int* __restrict__ flags) {
  if (blockIdx.x == 0) flags[threadIdx.x] = 0;
  int idx = blockIdx.x * 256 + threadIdx.x;   // T*128
  int t = idx >> 7;
  int d = idx & 127;
  h[idx] = emb[(size_t)x[t] * 128 + d];
}

// ---------------- weight casts (hi/lo split) ----------------
__global__ __launch_bounds__(256) void cast_split_kernel(const float* __restrict__ src,
                                                         bf16* __restrict__ hi,
                                                         bf16* __restrict__ lo, int n) {
  int i = blockIdx.x * 256 + threadIdx.x;
  if (i < n) { bf16 h, l; split_bf16(src[i], h, l); hi[i] = h; lo[i] = l; }
}

// x_proj: src [32][40][256] -> dst [32][64][256], rows 40..63 zero
__global__ __launch_bounds__(256) void cast_xproj_kernel(const float* __restrict__ src,
                                                         bf16* __restrict__ hi,
                                                         bf16* __restrict__ lo) {
  int i = blockIdx.x * 256 + threadIdx.x;   // 32*64*256
  int k = i & 255, n = (i >> 8) & 63, l = i >> 14;
  float v = (n < 40) ? src[((size_t)l * 40 + n) * 256 + k] : 0.f;
  bf16 h, lw; split_bf16(v, h, lw);
  hi[i] = h; lo[i] = lw;
}

// ---------------- rmsnorm -> bf16 hi/lo (layer-0 input only) ----------------
__global__ __launch_bounds__(256) void rmsnorm_split_kernel(const float* __restrict__ hin,
                                                            const float* __restrict__ w,
                                                            bf16* __restrict__ hout_h,
                                                            bf16* __restrict__ hout_l) {
  int row = blockIdx.x * 4 + (threadIdx.x >> 6);
  int lane = threadIdx.x & 63;
  float2 v = *(const float2*)&hin[(size_t)row * 128 + lane * 2];
  float ss = v.x * v.x + v.y * v.y;
  #pragma unroll
  for (int m = 1; m < 64; m <<= 1) ss += __shfl_xor(ss, m);
  float rstd = rsqrtf(ss * (1.0f / 128.0f) + 1e-5f);
  float2 wv = *(const float2*)&w[lane * 2];
  float o0 = v.x * rstd * wv.x, o1 = v.y * rstd * wv.y;
  __hip_bfloat162 ph, pl;
  bf16 hh, ll;
  split_bf16(o0, hh, ll); ph.x = hh; pl.x = ll;
  split_bf16(o1, hh, ll); ph.y = hh; pl.y = ll;
  *(__hip_bfloat162*)&hout_h[(size_t)row * 128 + lane * 2] = ph;
  *(__hip_bfloat162*)&hout_l[(size_t)row * 128 + lane * 2] = pl;
}

// ================= generic split-bf16 MFMA GEMM (head) =================
template <int BM, int BN, int WR, int WC, int EPI>
__global__ __launch_bounds__(256) void mfma_gemm(const bf16* __restrict__ AH,
                                                 const bf16* __restrict__ AL,
                                                 const bf16* __restrict__ WH,
                                                 const bf16* __restrict__ WL,
                                                 float* __restrict__ C,
                                                 const float* __restrict__ bias,
                                                 int Nc, int Kc) {
  constexpr int WTM = BM / WR, WTN = BN / WC;
  constexpr int U = WTM / 16, V = WTN / 16;
  __shared__ bf16 AsH[BM * 64];
  __shared__ bf16 AsL[BM * 64];
  __shared__ bf16 BsH[BN * 64];
  __shared__ bf16 BsL[BN * 64];
  int tid = threadIdx.x;
  int lane = tid & 63, wid = tid >> 6;
  int wr = wid / WC, wc = wid % WC;
  int row0 = blockIdx.x * BM, col0 = blockIdx.y * BN;
  int l15 = lane & 15, l4 = lane >> 4;
  f32x4 acc[U][V] = {};
  for (int k0 = 0; k0 < Kc; k0 += 64) {
    __syncthreads();
    #pragma unroll
    for (int it = 0; it < BM / 32; ++it) {
      int chunk = it * 256 + tid;
      int r = chunk >> 3;
      int clog = (chunk & 7) ^ (r & 7);
      size_t goff = (size_t)(row0 + r) * Kc + k0 + clog * 8;
      gload_lds16(AH + goff, &AsH[chunk * 8]);
      gload_lds16(AL + goff, &AsL[chunk * 8]);
    }
    #pragma unroll
    for (int it = 0; it < BN / 32; ++it) {
      int chunk = it * 256 + tid;
      int r = chunk >> 3;
      int clog = (chunk & 7) ^ (r & 7);
      size_t goff = (size_t)(col0 + r) * Kc + k0 + clog * 8;
      gload_lds16(WH + goff, &BsH[chunk * 8]);
      gload_lds16(WL + goff, &BsL[chunk * 8]);
    }
    __syncthreads();
    #pragma unroll
    for (int kk = 0; kk < 2; ++kk) {
      bf16x8 afh[U], afl[U], bfh[V], bfl[V];
      #pragma unroll
      for (int u = 0; u < U; ++u) {
        int r = wr * WTM + u * 16 + l15;
        int csw = (kk * 4 + l4) ^ (r & 7);
        afh[u] = *(const bf16x8*)&AsH[r * 64 + csw * 8];
        afl[u] = *(const bf16x8*)&AsL[r * 64 + csw * 8];
      }
      #pragma unroll
      for (int v = 0; v < V; ++v) {
        int r = wc * WTN + v * 16 + l15;
        int csw = (kk * 4 + l4) ^ (r & 7);
        bfh[v] = *(const bf16x8*)&BsH[r * 64 + csw * 8];
        bfl[v] = *(const bf16x8*)&BsL[r * 64 + csw * 8];
      }
      #pragma unroll
      for (int u = 0; u < U; ++u)
        #pragma unroll
        for (int v = 0; v < V; ++v) {
          acc[u][v] = __builtin_amdgcn_mfma_f32_16x16x32_bf16(afh[u], bfh[v], acc[u][v], 0, 0, 0);
          acc[u][v] = __builtin_amdgcn_mfma_f32_16x16x32_bf16(afl[u], bfh[v], acc[u][v], 0, 0, 0);
          acc[u][v] = __builtin_amdgcn_mfma_f32_16x16x32_bf16(afh[u], bfl[v], acc[u][v], 0, 0, 0);
        }
    }
  }
  #pragma unroll
  for (int u = 0; u < U; ++u) {
    int rbase = row0 + wr * WTM + u * 16 + l4 * 4;
    #pragma unroll
    for (int v = 0; v < V; ++v) {
      int col = col0 + wc * WTN + v * 16 + l15;
      #pragma unroll
      for (int q = 0; q < 4; ++q) {
        size_t off = (size_t)(rbase + q) * Nc + col;
        float val = acc[u][v][q];
        if (EPI == 2) val += bias[col];
        C[off] = val;
      }
    }
  }
}

// ================= in_proj (128x128, K=128): writes hzx(f32) / silu(gate)(f32) =================
__global__ __launch_bounds__(256) void inproj_kernel(const bf16* __restrict__ AH,
                                                     const bf16* __restrict__ AL,
                                                     const bf16* __restrict__ WH,
                                                     const bf16* __restrict__ WL,
                                                     float* __restrict__ hzx,
                                                     float* __restrict__ gate_f) {
  constexpr int BM = 128, BN = 128;
  __shared__ bf16 AsH[BM * 64];
  __shared__ bf16 AsL[BM * 64];
  __shared__ bf16 BsH[BN * 64];
  __shared__ bf16 BsL[BN * 64];
  int tid = threadIdx.x;
  int lane = tid & 63, wid = tid >> 6;
  int wr = wid >> 1, wc = wid & 1;
  int row0 = blockIdx.x * BM, col0 = blockIdx.y * BN;
  int l15 = lane & 15, l4 = lane >> 4;
  f32x4 acc[4][4] = {};
  for (int k0 = 0; k0 < 128; k0 += 64) {
    __syncthreads();
    #pragma unroll
    for (int it = 0; it < 4; ++it) {
      int chunk = it * 256 + tid;
      int r = chunk >> 3;
      int clog = (chunk & 7) ^ (r & 7);
      size_t goff = (size_t)(row0 + r) * 128 + k0 + clog * 8;
      gload_lds16(AH + goff, &AsH[chunk * 8]);
      gload_lds16(AL + goff, &AsL[chunk * 8]);
      size_t woff = (size_t)(col0 + r) * 128 + k0 + clog * 8;
      gload_lds16(WH + woff, &BsH[chunk * 8]);
      gload_lds16(WL + woff, &BsL[chunk * 8]);
    }
    __syncthreads();
    #pragma unroll
    for (int kk = 0; kk < 2; ++kk) {
      bf16x8 afh[4], afl[4], bfh[4], bfl[4];
      #pragma unroll
      for (int u = 0; u < 4; ++u) {
        int r = wr * 64 + u * 16 + l15;
        int csw = (kk * 4 + l4) ^ (r & 7);
        afh[u] = *(const bf16x8*)&AsH[r * 64 + csw * 8];
        afl[u] = *(const bf16x8*)&AsL[r * 64 + csw * 8];
      }
      #pragma unroll
      for (int v = 0; v < 4; ++v) {
        int r = wc * 64 + v * 16 + l15;
        int csw = (kk * 4 + l4) ^ (r & 7);
        bfh[v] = *(const bf16x8*)&BsH[r * 64 + csw * 8];
        bfl[v] = *(const bf16x8*)&BsL[r * 64 + csw * 8];
      }
      #pragma unroll
      for (int u = 0; u < 4; ++u)
        #pragma unroll
        for (int v = 0; v < 4; ++v) {
          acc[u][v] = __builtin_amdgcn_mfma_f32_16x16x32_bf16(afh[u], bfh[v], acc[u][v], 0, 0, 0);
          acc[u][v] = __builtin_amdgcn_mfma_f32_16x16x32_bf16(afl[u], bfh[v], acc[u][v], 0, 0, 0);
          acc[u][v] = __builtin_amdgcn_mfma_f32_16x16x32_bf16(afh[u], bfl[v], acc[u][v], 0, 0, 0);
        }
    }
  }
  bool isgate = (col0 >= 256);
  #pragma unroll
  for (int u = 0; u < 4; ++u) {
    int rbase = row0 + wr * 64 + u * 16 + l4 * 4;
    #pragma unroll
    for (int v = 0; v < 4; ++v) {
      int col = col0 + wc * 64 + v * 16 + l15;
      #pragma unroll
      for (int q = 0; q < 4; ++q) {
        float val = acc[u][v][q];
        if (!isgate) {
          hzx[(size_t)(rbase + q) * 256 + col] = val;
        } else {
          float s = val / (1.0f + __expf(-val));
          gate_f[(size_t)(rbase + q) * 256 + (col - 256)] = s;
        }
      }
    }
  }
}

// ================= x_proj (32x64, K=256): fused conv+silu staging, writes hs(bf162) + xp + dt =================
__global__ __launch_bounds__(256) void xproj_dt_kernel(const float* __restrict__ hzx,
                                                       const float* __restrict__ cw,
                                                       const float* __restrict__ cb,
                                                       const bf16* __restrict__ WH,
                                                       const bf16* __restrict__ WL,
                                                       const float* __restrict__ Wdt,
                                                       const float* __restrict__ bdt,
                                                       __hip_bfloat162* __restrict__ hs_p,
                                                       float* __restrict__ xp,
                                                       float* __restrict__ dtb) {
  __shared__ bf16 AsH[32 * 64];
  __shared__ bf16 AsL[32 * 64];
  __shared__ bf16 BsH[64 * 64];
  __shared__ bf16 BsL[64 * 64];
  __shared__ float xq[32][8];
  int tid = threadIdx.x;
  int lane = tid & 63, wid = tid >> 6;
  int wr = wid >> 1, wc = wid & 1;   // wave tile 16x32
  int row0 = blockIdx.x * 32;
  int l15 = lane & 15, l4 = lane >> 4;
  int r = tid >> 3, cslot = tid & 7;
  int tok = row0 + r;
  int lpos = tok & (LSEQ - 1);   // 32 | LSEQ, blocks never straddle sequences
  f32x4 acc[1][2] = {};
  for (int k0 = 0; k0 < 256; k0 += 64) {
    __syncthreads();
    {
      int kb = k0 + ((cslot ^ (r & 7)) << 3);
      const float* hp = &hzx[(size_t)tok * 256 + kb];
      float x3[8], x2[8], x1[8], x0[8];
      *(float4*)&x3[0] = *(const float4*)(hp);
      *(float4*)&x3[4] = *(const float4*)(hp + 4);
      if (lpos >= 1) { *(float4*)&x2[0] = *(const float4*)(hp - 256); *(float4*)&x2[4] = *(const float4*)(hp - 252); }
      else { *(float4*)&x2[0] = make_float4(0,0,0,0); *(float4*)&x2[4] = make_float4(0,0,0,0); }
      if (lpos >= 2) { *(float4*)&x1[0] = *(const float4*)(hp - 512); *(float4*)&x1[4] = *(const float4*)(hp - 508); }
      else { *(float4*)&x1[0] = make_float4(0,0,0,0); *(float4*)&x1[4] = make_float4(0,0,0,0); }
      if (lpos >= 3) { *(float4*)&x0[0] = *(const float4*)(hp - 768); *(float4*)&x0[4] = *(const float4*)(hp - 764); }
      else { *(float4*)&x0[0] = make_float4(0,0,0,0); *(float4*)&x0[4] = make_float4(0,0,0,0); }
      bf16 tH[8], tL[8];
      __hip_bfloat162 pk[8];
      #pragma unroll
      for (int j = 0; j < 8; ++j) {
        float4 w = *(const float4*)&cw[(kb + j) * 4];
        float s = cb[kb + j];
        s = fmaf(x0[j], w.x, s);
        s = fmaf(x1[j], w.y, s);
        s = fmaf(x2[j], w.z, s);
        s = fmaf(x3[j], w.w, s);
        s = s / (1.0f + __expf(-s));
        split_bf16(s, tH[j], tL[j]);
        pk[j].x = tH[j]; pk[j].y = tL[j];
      }
      *(bf16x8*)&AsH[tid * 8] = *(const bf16x8*)tH;
      *(bf16x8*)&AsL[tid * 8] = *(const bf16x8*)tL;
      *(float4*)&hs_p[(size_t)tok * 256 + kb]     = *(const float4*)&pk[0];
      *(float4*)&hs_p[(size_t)tok * 256 + kb + 4] = *(const float4*)&pk[4];
    }
    #pragma unroll
    for (int it = 0; it < 2; ++it) {
      int chunk = it * 256 + tid;
      int rr = chunk >> 3;
      int clog = (chunk & 7) ^ (rr & 7);
      size_t goff = (size_t)rr * 256 + k0 + clog * 8;
      gload_lds16(WH + goff, &BsH[chunk * 8]);
      gload_lds16(WL + goff, &BsL[chunk * 8]);
    }
    __syncthreads();
    #pragma unroll
    for (int kk = 0; kk < 2; ++kk) {
      bf16x8 afh, afl, bfh[2], bfl[2];
      {
        int rr = wr * 16 + l15;
        int csw = (kk * 4 + l4) ^ (rr & 7);
        afh = *(const bf16x8*)&AsH[rr * 64 + csw * 8];
        afl = *(const bf16x8*)&AsL[rr * 64 + csw * 8];
      }
      #pragma unroll
      for (int v = 0; v < 2; ++v) {
        int rr = wc * 32 + v * 16 + l15;
        int csw = (kk * 4 + l4) ^ (rr & 7);
        bfh[v] = *(const bf16x8*)&BsH[rr * 64 + csw * 8];
        bfl[v] = *(const bf16x8*)&BsL[rr * 64 + csw * 8];
      }
      #pragma unroll
      for (int v = 0; v < 2; ++v) {
        acc[0][v] = __builtin_amdgcn_mfma_f32_16x16x32_bf16(afh, bfh[v], acc[0][v], 0, 0, 0);
        acc[0][v] = __builtin_amdgcn_mfma_f32_16x16x32_bf16(afl, bfh[v], acc[0][v], 0, 0, 0);
        acc[0][v] = __builtin_amdgcn_mfma_f32_16x16x32_bf16(afh, bfl[v], acc[0][v], 0, 0, 0);
      }
    }
  }
  {
    int rbase = wr * 16 + l4 * 4;
    #pragma unroll
    for (int v = 0; v < 2; ++v) {
      int col = wc * 32 + v * 16 + l15;
      #pragma unroll
      for (int q = 0; q < 4; ++q) {
        float val = acc[0][v][q];
        xp[(size_t)(row0 + rbase + q) * 64 + col] = val;
        if (col < 8) xq[rbase + q][col] = val;
      }
    }
  }
  __syncthreads();
  {
    int i = tid;
    const float* wr8 = Wdt + i * 8;
    float w0 = wr8[0], w1 = wr8[1], w2 = wr8[2], w3 = wr8[3];
    float w4 = wr8[4], w5 = wr8[5], w6 = wr8[6], w7 = wr8[7];
    float bv = bdt[i];
    #pragma unroll 4
    for (int tt = 0; tt < 32; ++tt) {
      const float* q = xq[tt];
      float s = bv;
      s = fmaf(q[0], w0, s); s = fmaf(q[1], w1, s);
      s = fmaf(q[2], w2, s); s = fmaf(q[3], w3, s);
      s = fmaf(q[4], w4, s); s = fmaf(q[5], w5, s);
      s = fmaf(q[6], w6, s); s = fmaf(q[7], w7, s);
      float sp = (s > 20.0f) ? s : log1pf(__expf(s));
      dtb[(size_t)(row0 + tt) * 256 + i] = sp;
    }
  }
}

// ================= out_proj (32x128, K=256) + residual + fused next-layer RMSNorm =================
__global__ __launch_bounds__(256) void outproj_norm_kernel(const bf16* __restrict__ AH,
                                                           const bf16* __restrict__ AL,
                                                           const bf16* __restrict__ WH,
                                                           const bf16* __restrict__ WL,
                                                           const float* __restrict__ nw,
                                                           float* __restrict__ Ch,
                                                           bf16* __restrict__ hn_h,
                                                           bf16* __restrict__ hn_l) {
  constexpr int BM = 32, BN = 128;
  __shared__ bf16 AsH[BM * 64];
  __shared__ bf16 AsL[BM * 64];
  __shared__ bf16 BsH[BN * 64];
  __shared__ bf16 BsL[BN * 64];
  __shared__ float ssq[32][2];
  int tid = threadIdx.x;
  int lane = tid & 63, wid = tid >> 6;
  int wr = wid >> 1, wc = wid & 1;    // wave tile 16x64
  int row0 = blockIdx.x * BM;
  int l15 = lane & 15, l4 = lane >> 4;
  f32x4 acc[1][4] = {};
  for (int k0 = 0; k0 < 256; k0 += 64) {
    __syncthreads();
    {
      int chunk = tid;
      int r = chunk >> 3;
      int clog = (chunk & 7) ^ (r & 7);
      size_t goff = (size_t)(row0 + r) * 256 + k0 + clog * 8;
      gload_lds16(AH + goff, &AsH[chunk * 8]);
      gload_lds16(AL + goff, &AsL[chunk * 8]);
    }
    #pragma unroll
    for (int it = 0; it < 4; ++it) {
      int chunk = it * 256 + tid;
      int r = chunk >> 3;
      int clog = (chunk & 7) ^ (r & 7);
      size_t goff = (size_t)r * 256 + k0 + clog * 8;
      gload_lds16(WH + goff, &BsH[chunk * 8]);
      gload_lds16(WL + goff, &BsL[chunk * 8]);
    }
    __syncthreads();
    #pragma unroll
    for (int kk = 0; kk < 2; ++kk) {
      bf16x8 afh, afl, bfh[4], bfl[4];
      {
        int r = wr * 16 + l15;
        int csw = (kk * 4 + l4) ^ (r & 7);
        afh = *(const bf16x8*)&AsH[r * 64 + csw * 8];
        afl = *(const bf16x8*)&AsL[r * 64 + csw * 8];
      }
      #pragma unroll
      for (int v = 0; v < 4; ++v) {
        int r = wc * 64 + v * 16 + l15;
        int csw = (kk * 4 + l4) ^ (r & 7);
        bfh[v] = *(const bf16x8*)&BsH[r * 64 + csw * 8];
        bfl[v] = *(const bf16x8*)&BsL[r * 64 + csw * 8];
      }
      #pragma unroll
      for (int v = 0; v < 4; ++v) {
        acc[0][v] = __builtin_amdgcn_mfma_f32_16x16x32_bf16(afh, bfh[v], acc[0][v], 0, 0, 0);
        acc[0][v] = __builtin_amdgcn_mfma_f32_16x16x32_bf16(afl, bfh[v], acc[0][v], 0, 0, 0);
        acc[0][v] = __builtin_amdgcn_mfma_f32_16x16x32_bf16(afh, bfl[v], acc[0][v], 0, 0, 0);
      }
    }
  }
  int rloc = wr * 16 + l4 * 4;
  float vals[4][4];   // [q][v]
  #pragma unroll
  for (int v = 0; v < 4; ++v) {
    int col = wc * 64 + v * 16 + l15;
    #pragma unroll
    for (int q = 0; q < 4; ++q) {
      size_t off = (size_t)(row0 + rloc + q) * 128 + col;
      float val = acc[0][v][q] + Ch[off];
      vals[q][v] = val;
      Ch[off] = val;
    }
  }
  #pragma unroll
  for (int q = 0; q < 4; ++q) {
    float ss = vals[q][0] * vals[q][0] + vals[q][1] * vals[q][1]
             + vals[q][2] * vals[q][2] + vals[q][3] * vals[q][3];
    ss += __shfl_xor(ss, 1, 16);
    ss += __shfl_xor(ss, 2, 16);
    ss += __shfl_xor(ss, 4, 16);
    ss += __shfl_xor(ss, 8, 16);
    if (l15 == 0) ssq[rloc + q][wc] = ss;
  }
  __syncthreads();
  #pragma unroll
  for (int q = 0; q < 4; ++q) {
    float rstd = rsqrtf((ssq[rloc + q][0] + ssq[rloc + q][1]) * (1.0f / 128.0f) + 1e-5f);
    #pragma unroll
    for (int v = 0; v < 4; ++v) {
      int col = wc * 64 + v * 16 + l15;
      float o = vals[q][v] * rstd * nw[col];
      bf16 hh, ll;
      split_bf16(o, hh, ll);
      size_t off = (size_t)(row0 + rloc + q) * 128 + col;
      hn_h[off] = hh;
      hn_l[off] = ll;
    }
  }
}

// ================= fused scan: phase A -> decoupled lookback -> phase C =================
// grid 256 = (b<<5)|c; one block per CU guaranteed resident -> spin-safe without coop launch.
__global__ __launch_bounds__(256) void scan_fused_kernel(const float* __restrict__ dtb,
                                                         const __hip_bfloat162* __restrict__ hs_p,
                                                         const float* __restrict__ xp,
                                                         const float* __restrict__ A_log,
                                                         const float* __restrict__ Dp,
                                                         const float* __restrict__ gate_f,
                                                         float* __restrict__ Pb,
                                                         float* __restrict__ Sb,
                                                         float* __restrict__ Tb,
                                                         int* __restrict__ flags,
                                                         int epoch,
                                                         bf16* __restrict__ y_h,
                                                         bf16* __restrict__ y_l) {
  int bc = blockIdx.x;
  int b = bc >> 5, c = bc & 31;
  int i = threadIdx.x;
  __shared__ int stat;
  float A[16];
  {
    const float4* ap = (const float4*)&A_log[i * 16];
    #pragma unroll
    for (int q = 0; q < 4; ++q) {
      float4 a = ap[q];
      A[q * 4 + 0] = -__expf(a.x); A[q * 4 + 1] = -__expf(a.y);
      A[q * 4 + 2] = -__expf(a.z); A[q * 4 + 3] = -__expf(a.w);
    }
  }
  // ---- phase A: chunk-local (P, S) ----
  float P[16], S[16];
  #pragma unroll
  for (int n = 0; n < 16; ++n) { P[n] = 1.0f; S[n] = 0.0f; }
  int t0 = b * LSEQ + c * CHL;
  for (int l = 0; l < CHL; ++l) {
    size_t t = t0 + l;
    float dtv = dtb[t * 256 + i];
    __hip_bfloat162 hp = hs_p[t * 256 + i];
    float hsv = __bfloat162float(hp.x) + __bfloat162float(hp.y);
    float dh = dtv * hsv;
    float Bv[16];
    #pragma unroll
    for (int q = 0; q < 4; ++q) {
      float4 bv = *(const float4*)&xp[t * 64 + 8 + q * 4];
      Bv[q * 4 + 0] = bv.x; Bv[q * 4 + 1] = bv.y; Bv[q * 4 + 2] = bv.z; Bv[q * 4 + 3] = bv.w;
    }
    #pragma unroll
    for (int n = 0; n < 16; ++n) {
      float e = __expf(dtv * A[n]);
      P[n] *= e;
      S[n] = fmaf(S[n], e, dh * Bv[n]);
    }
  }
  size_t base = ((size_t)bc << 12) + i * 16;
  #pragma unroll
  for (int q = 0; q < 4; ++q) {
    *(float4*)&Pb[base + q * 4] = make_float4(P[q * 4], P[q * 4 + 1], P[q * 4 + 2], P[q * 4 + 3]);
    *(float4*)&Sb[base + q * 4] = make_float4(S[q * 4], S[q * 4 + 1], S[q * 4 + 2], S[q * 4 + 3]);
  }
  if (c == 0) {
    #pragma unroll
    for (int q = 0; q < 4; ++q)
      *(float4*)&Tb[base + q * 4] = make_float4(S[q * 4], S[q * 4 + 1], S[q * 4 + 2], S[q * 4 + 3]);
  }
  __syncthreads();
  if (threadIdx.x == 0) {
    __threadfence();
    __hip_atomic_store(&flags[bc], c == 0 ? 2 * epoch + 1 : 2 * epoch,
                       __ATOMIC_RELEASE, __HIP_MEMORY_SCOPE_AGENT);
  }
  // ---- decoupled lookback: prefix state before this chunk ----
  float pref[16];
  #pragma unroll
  for (int n = 0; n < 16; ++n) pref[n] = 0.0f;
  if (c > 0) {
    float Ac[16];
    #pragma unroll
    for (int n = 0; n < 16; ++n) Ac[n] = 1.0f;
    for (int j = c - 1; j >= 0; --j) {
      __syncthreads();
      if (threadIdx.x == 0) {
        int f;
        do {
          f = __hip_atomic_load(&flags[(b << 5) + j], __ATOMIC_ACQUIRE, __HIP_MEMORY_SCOPE_AGENT);
        } while (f < 2 * epoch);
        stat = f;
      }
      __syncthreads();
      int f = stat;
      __threadfence();
      size_t jb = ((size_t)((b << 5) + j) << 12) + i * 16;
      if (f == 2 * epoch + 1) {
        #pragma unroll
        for (int q = 0; q < 4; ++q) {
          float4 tv = *(const float4*)&Tb[jb + q * 4];
          pref[q * 4 + 0] = fmaf(Ac[q * 4 + 0], tv.x, pref[q * 4 + 0]);
          pref[q * 4 + 1] = fmaf(Ac[q * 4 + 1], tv.y, pref[q * 4 + 1]);
          pref[q * 4 + 2] = fmaf(Ac[q * 4 + 2], tv.z, pref[q * 4 + 2]);
          pref[q * 4 + 3] = fmaf(Ac[q * 4 + 3], tv.w, pref[q * 4 + 3]);
        }
        break;
      } else {
        #pragma unroll
        for (int q = 0; q < 4; ++q) {
          float4 sv = *(const float4*)&Sb[jb + q * 4];
          float4 pv = *(const float4*)&Pb[jb + q * 4];
          pref[q * 4 + 0] = fmaf(Ac[q * 4 + 0], sv.x, pref[q * 4 + 0]);
          pref[q * 4 + 1] = fmaf(Ac[q * 4 + 1], sv.y, pref[q * 4 + 1]);
          pref[q * 4 + 2] = fmaf(Ac[q * 4 + 2], sv.z, pref[q * 4 + 2]);
          pref[q * 4 + 3] = fmaf(Ac[q * 4 + 3], sv.w, pref[q * 4 + 3]);
          Ac[q * 4 + 0] *= pv.x; Ac[q * 4 + 1] *= pv.y;
          Ac[q * 4 + 2] *= pv.z; Ac[q * 4 + 3] *= pv.w;
        }
      }
    }
    // publish inclusive for this chunk
    #pragma unroll
    for (int q = 0; q < 4; ++q) {
      float4 tv;
      tv.x = fmaf(P[q * 4 + 0], pref[q * 4 + 0], S[q * 4 + 0]);
      tv.y = fmaf(P[q * 4 + 1], pref[q * 4 + 1], S[q * 4 + 1]);
      tv.z = fmaf(P[q * 4 + 2], pref[q * 4 + 2], S[q * 4 + 2]);
      tv.w = fmaf(P[q * 4 + 3], pref[q * 4 + 3], S[q * 4 + 3]);
      *(float4*)&Tb[base + q * 4] = tv;
    }
    __syncthreads();
    if (threadIdx.x == 0) {
      __threadfence();
      __hip_atomic_store(&flags[bc], 2 * epoch + 1, __ATOMIC_RELEASE, __HIP_MEMORY_SCOPE_AGENT);
    }
  }
  // ---- phase C: replay with prefix, emit y ----
  float st[16];
  #pragma unroll
  for (int n = 0; n < 16; ++n) st[n] = pref[n];
  float Dv = Dp[i];
  for (int l = 0; l < CHL; ++l) {
    size_t t = t0 + l;
    float dtv = dtb[t * 256 + i];
    __hip_bfloat162 hp = hs_p[t * 256 + i];
    float hsv = __bfloat162float(hp.x) + __bfloat162float(hp.y);
    float dh = dtv * hsv;
    float Bv[16], Cv[16];
    #pragma unroll
    for (int q = 0; q < 4; ++q) {
      float4 bv = *(const float4*)&xp[t * 64 + 8 + q * 4];
      Bv[q * 4 + 0] = bv.x; Bv[q * 4 + 1] = bv.y; Bv[q * 4 + 2] = bv.z; Bv[q * 4 + 3] = bv.w;
      float4 cv = *(const float4*)&xp[t * 64 + 24 + q * 4];
      Cv[q * 4 + 0] = cv.x; Cv[q * 4 + 1] = cv.y; Cv[q * 4 + 2] = cv.z; Cv[q * 4 + 3] = cv.w;
    }
    float y0 = 0.f, y1 = 0.f, y2 = 0.f, y3 = 0.f;
    #pragma unroll
    for (int q = 0; q < 4; ++q) {
      float e0 = __expf(dtv * A[q * 4 + 0]);
      float e1 = __expf(dtv * A[q * 4 + 1]);
      float e2 = __expf(dtv * A[q * 4 + 2]);
      float e3 = __expf(dtv * A[q * 4 + 3]);
      st[q * 4 + 0] = fmaf(st[q * 4 + 0], e0, dh * Bv[q * 4 + 0]);
      st[q * 4 + 1] = fmaf(st[q * 4 + 1], e1, dh * Bv[q * 4 + 1]);
      st[q * 4 + 2] = fmaf(st[q * 4 + 2], e2, dh * Bv[q * 4 + 2]);
      st[q * 4 + 3] = fmaf(st[q * 4 + 3], e3, dh * Bv[q * 4 + 3]);
      y0 = fmaf(st[q * 4 + 0], Cv[q * 4 + 0], y0);
      y1 = fmaf(st[q * 4 + 1], Cv[q * 4 + 1], y1);
      y2 = fmaf(st[q * 4 + 2], Cv[q * 4 + 2], y2);
      y3 = fmaf(st[q * 4 + 3], Cv[q * 4 + 3], y3);
    }
    float y = ((y0 + y1) + (y2 + y3)) + hsv * Dv;
    float g = gate_f[t * 256 + i];
    float val = y * g;
    bf16 hh, ll;
    split_bf16(val, hh, ll);
    y_h[t * 256 + i] = hh;
    y_l[t * 256 + i] = ll;
  }
}

extern "C" void kernel_launch(void* const* d_in, const int* in_sizes, int n_in,
                              void* d_out, int out_size, void* d_ws, size_t ws_size,
                              hipStream_t stream) {
  const int* x           = (const int*)d_in[0];
  const float* embed     = (const float*)d_in[1];
  const float* in_proj_w = (const float*)d_in[2];
  const float* conv_w    = (const float*)d_in[3];
  const float* conv_b    = (const float*)d_in[4];
  const float* x_proj_w  = (const float*)d_in[5];
  const float* dt_proj_w = (const float*)d_in[6];
  const float* dt_proj_b = (const float*)d_in[7];
  const float* A_log     = (const float*)d_in[8];
  const float* Dp        = (const float*)d_in[9];
  const float* out_proj_w= (const float*)d_in[10];
  const float* norm_w    = (const float*)d_in[11];
  const float* norm_f_w  = (const float*)d_in[12];
  const float* head_w    = (const float*)d_in[13];
  const float* head_b    = (const float*)d_in[14];

  float* out = (float*)d_out;
  float* ws  = (float*)d_ws;

  // ---- d_out scratch map (f32 word offsets; budget 33,554,432) ----
  float* hzx     = out;                          //  4,194,304 (T*256 f32)
  float* gate_f  = out + 4194304;                //  4,194,304 (T*256 f32)
  __hip_bfloat162* hs_p = (__hip_bfloat162*)(out + 8388608);   // 4,194,304 w (T*256 bf162)
  float* dtb     = out + 12582912;               //  4,194,304 (T*256 f32)
  float* xp      = out + 16777216;               //  1,048,576 (T*64 f32)
  bf16*  y_h     = (bf16*)(out + 17825792);      //  2,097,152 w
  bf16*  y_l     = (bf16*)(out + 19922944);      //  2,097,152 w
  float* h       = out + 22020096;               //  2,097,152 (T*128 residual)
  bf16*  w_in_h  = (bf16*)(out + 24117248);      //  1,048,576 w
  bf16*  w_in_l  = (bf16*)(out + 25165824);      //  1,048,576 w
  bf16*  w_x_h   = (bf16*)(out + 26214400);      //    262,144 w (padded 64 rows)
  bf16*  w_x_l   = (bf16*)(out + 26476544);
  bf16*  w_out_h = (bf16*)(out + 26738688);      //    524,288 w
  bf16*  w_out_l = (bf16*)(out + 27262976);
  float* Pb      = out + 27787264;               //  1,048,576 (8*NCH*4096)
  float* Sb      = out + 28835840;               //  1,048,576
  float* Tb      = out + 29884416;               //  1,048,576 -> ends 30,932,992

  // ---- ws scratch — live through the head GEMM ----
  bf16* hn_h     = (bf16*)ws;                    // T*128 bf16
  bf16* hn_l     = (bf16*)(ws + 1048576);
  bf16* w_head_h = (bf16*)(ws + 2097152);        // 2048*128 bf16
  bf16* w_head_l = (bf16*)(ws + 2228224);
  int*  flags    = (int*)(ws + 2400000);         // 256 ints

  cast_split_kernel<<<8192, 256, 0, stream>>>(in_proj_w, w_in_h, w_in_l, 2097152);
  cast_xproj_kernel<<<2048, 256, 0, stream>>>(x_proj_w, w_x_h, w_x_l);
  cast_split_kernel<<<4096, 256, 0, stream>>>(out_proj_w, w_out_h, w_out_l, 1048576);
  cast_split_kernel<<<1024, 256, 0, stream>>>(head_w, w_head_h, w_head_l, 262144);

  embed_kernel<<<8192, 256, 0, stream>>>(x, embed, h, flags);
  rmsnorm_split_kernel<<<4096, 256, 0, stream>>>(h, norm_w, hn_h, hn_l);

  for (int l = 0; l < 32; ++l) {
    inproj_kernel<<<dim3(128, 4), 256, 0, stream>>>(
        hn_h, hn_l, w_in_h + (size_t)l * 512 * 128, w_in_l + (size_t)l * 512 * 128,
        hzx, gate_f);
    xproj_dt_kernel<<<512, 256, 0, stream>>>(
        hzx, conv_w + l * 1024, conv_b + l * 256,
        w_x_h + (size_t)l * 64 * 256, w_x_l + (size_t)l * 64 * 256,
        dt_proj_w + l * 2048, dt_proj_b + l * 256, hs_p, xp, dtb);
    scan_fused_kernel<<<256, 256, 0, stream>>>(
        dtb, hs_p, xp, A_log + l * 4096, Dp + l * 256, gate_f,
        Pb, Sb, Tb, flags, l + 1, y_h, y_l);
    const float* nwnext = (l < 31) ? (norm_w + (l + 1) * 128) : norm_f_w;
    outproj_norm_kernel<<<512, 256, 0, stream>>>(
        y_h, y_l, w_out_h + (size_t)l * 128 * 256, w_out_l + (size_t)l * 128 * 256,
        nwnext, h, hn_h, hn_l);
  }

  mfma_gemm<128, 128, 2, 2, 2><<<dim3(128, 16), 256, 0, stream>>>(
      hn_h, hn_l, w_head_h, w_head_l, out, head_b, 2048, 128);
}

// Round 14
// 3556.089 us; speedup vs baseline: 3.6961x; 3.6961x over previous
//
#include <hip/hip_runtime.h>
#include <hip/hip_bf16.h>

#define LSEQ 2048
#define NCH 64          // chunks per sequence
#define CHL 32          // chunk length (NCH*CHL == LSEQ)

typedef __attribute__((ext_vector_type(8))) short bf16x8;
typedef __attribute__((ext_vector_type(4))) float f32x4;
typedef __hip_bfloat16 bf16;

__device__ __forceinline__ void gload_lds16(const void* g, void* l) {
  __builtin_amdgcn_global_load_lds(
      (const __attribute__((address_space(1))) void*)g,
      (__attribute__((address_space(3))) void*)l, 16, 0, 0);
}

__device__ __forceinline__ void split_bf16(float v, bf16& h, bf16& l) {
  h = __float2bfloat16(v);
  l = __float2bfloat16(v - __bfloat162float(h));
}

// ---------------- embed ----------------
__global__ __launch_bounds__(256) void embed_kernel(const int* __restrict__ x,
                                                    const float* __restrict__ emb,
                                                    float* __restrict__ h) {
  int idx = blockIdx.x * 256 + threadIdx.x;   // T*128
  int t = idx >> 7;
  int d = idx & 127;
  h[idx] = emb[(size_t)x[t] * 128 + d];
}

// ---------------- weight casts (hi/lo split) ----------------
__global__ __launch_bounds__(256) void cast_split_kernel(const float* __restrict__ src,
                                                         bf16* __restrict__ hi,
                                                         bf16* __restrict__ lo, int n) {
  int i = blockIdx.x * 256 + threadIdx.x;
  if (i < n) { bf16 h, l; split_bf16(src[i], h, l); hi[i] = h; lo[i] = l; }
}

// x_proj: src [32][40][256] -> dst [32][64][256], rows 40..63 zero
__global__ __launch_bounds__(256) void cast_xproj_kernel(const float* __restrict__ src,
                                                         bf16* __restrict__ hi,
                                                         bf16* __restrict__ lo) {
  int i = blockIdx.x * 256 + threadIdx.x;   // 32*64*256
  int k = i & 255, n = (i >> 8) & 63, l = i >> 14;
  float v = (n < 40) ? src[((size_t)l * 40 + n) * 256 + k] : 0.f;
  bf16 h, lw; split_bf16(v, h, lw);
  hi[i] = h; lo[i] = lw;
}

// ---------------- rmsnorm -> bf16 hi/lo (layer-0 input only) ----------------
__global__ __launch_bounds__(256) void rmsnorm_split_kernel(const float* __restrict__ hin,
                                                            const float* __restrict__ w,
                                                            bf16* __restrict__ hout_h,
                                                            bf16* __restrict__ hout_l) {
  int row = blockIdx.x * 4 + (threadIdx.x >> 6);
  int lane = threadIdx.x & 63;
  float2 v = *(const float2*)&hin[(size_t)row * 128 + lane * 2];
  float ss = v.x * v.x + v.y * v.y;
  #pragma unroll
  for (int m = 1; m < 64; m <<= 1) ss += __shfl_xor(ss, m);
  float rstd = rsqrtf(ss * (1.0f / 128.0f) + 1e-5f);
  float2 wv = *(const float2*)&w[lane * 2];
  float o0 = v.x * rstd * wv.x, o1 = v.y * rstd * wv.y;
  __hip_bfloat162 ph, pl;
  bf16 hh, ll;
  split_bf16(o0, hh, ll); ph.x = hh; pl.x = ll;
  split_bf16(o1, hh, ll); ph.y = hh; pl.y = ll;
  *(__hip_bfloat162*)&hout_h[(size_t)row * 128 + lane * 2] = ph;
  *(__hip_bfloat162*)&hout_l[(size_t)row * 128 + lane * 2] = pl;
}

// ================= generic split-bf16 MFMA GEMM (head) =================
template <int BM, int BN, int WR, int WC, int EPI>
__global__ __launch_bounds__(256) void mfma_gemm(const bf16* __restrict__ AH,
                                                 const bf16* __restrict__ AL,
                                                 const bf16* __restrict__ WH,
                                                 const bf16* __restrict__ WL,
                                                 float* __restrict__ C,
                                                 const float* __restrict__ bias,
                                                 int Nc, int Kc) {
  constexpr int WTM = BM / WR, WTN = BN / WC;
  constexpr int U = WTM / 16, V = WTN / 16;
  __shared__ bf16 AsH[BM * 64];
  __shared__ bf16 AsL[BM * 64];
  __shared__ bf16 BsH[BN * 64];
  __shared__ bf16 BsL[BN * 64];
  int tid = threadIdx.x;
  int lane = tid & 63, wid = tid >> 6;
  int wr = wid / WC, wc = wid % WC;
  int row0 = blockIdx.x * BM, col0 = blockIdx.y * BN;
  int l15 = lane & 15, l4 = lane >> 4;
  f32x4 acc[U][V] = {};
  for (int k0 = 0; k0 < Kc; k0 += 64) {
    __syncthreads();
    #pragma unroll
    for (int it = 0; it < BM / 32; ++it) {
      int chunk = it * 256 + tid;
      int r = chunk >> 3;
      int clog = (chunk & 7) ^ (r & 7);
      size_t goff = (size_t)(row0 + r) * Kc + k0 + clog * 8;
      gload_lds16(AH + goff, &AsH[chunk * 8]);
      gload_lds16(AL + goff, &AsL[chunk * 8]);
    }
    #pragma unroll
    for (int it = 0; it < BN / 32; ++it) {
      int chunk = it * 256 + tid;
      int r = chunk >> 3;
      int clog = (chunk & 7) ^ (r & 7);
      size_t goff = (size_t)(col0 + r) * Kc + k0 + clog * 8;
      gload_lds16(WH + goff, &BsH[chunk * 8]);
      gload_lds16(WL + goff, &BsL[chunk * 8]);
    }
    __syncthreads();
    #pragma unroll
    for (int kk = 0; kk < 2; ++kk) {
      bf16x8 afh[U], afl[U], bfh[V], bfl[V];
      #pragma unroll
      for (int u = 0; u < U; ++u) {
        int r = wr * WTM + u * 16 + l15;
        int csw = (kk * 4 + l4) ^ (r & 7);
        afh[u] = *(const bf16x8*)&AsH[r * 64 + csw * 8];
        afl[u] = *(const bf16x8*)&AsL[r * 64 + csw * 8];
      }
      #pragma unroll
      for (int v = 0; v < V; ++v) {
        int r = wc * WTN + v * 16 + l15;
        int csw = (kk * 4 + l4) ^ (r & 7);
        bfh[v] = *(const bf16x8*)&BsH[r * 64 + csw * 8];
        bfl[v] = *(const bf16x8*)&BsL[r * 64 + csw * 8];
      }
      #pragma unroll
      for (int u = 0; u < U; ++u)
        #pragma unroll
        for (int v = 0; v < V; ++v) {
          acc[u][v] = __builtin_amdgcn_mfma_f32_16x16x32_bf16(afh[u], bfh[v], acc[u][v], 0, 0, 0);
          acc[u][v] = __builtin_amdgcn_mfma_f32_16x16x32_bf16(afl[u], bfh[v], acc[u][v], 0, 0, 0);
          acc[u][v] = __builtin_amdgcn_mfma_f32_16x16x32_bf16(afh[u], bfl[v], acc[u][v], 0, 0, 0);
        }
    }
  }
  #pragma unroll
  for (int u = 0; u < U; ++u) {
    int rbase = row0 + wr * WTM + u * 16 + l4 * 4;
    #pragma unroll
    for (int v = 0; v < V; ++v) {
      int col = col0 + wc * WTN + v * 16 + l15;
      #pragma unroll
      for (int q = 0; q < 4; ++q) {
        size_t off = (size_t)(rbase + q) * Nc + col;
        float val = acc[u][v][q];
        if (EPI == 2) val += bias[col];
        C[off] = val;
      }
    }
  }
}

// ================= in_proj (128x128, K=128): writes hzx(f32) / silu(gate)(f32) =================
__global__ __launch_bounds__(256) void inproj_kernel(const bf16* __restrict__ AH,
                                                     const bf16* __restrict__ AL,
                                                     const bf16* __restrict__ WH,
                                                     const bf16* __restrict__ WL,
                                                     float* __restrict__ hzx,
                                                     float* __restrict__ gate_f) {
  constexpr int BM = 128, BN = 128;
  __shared__ bf16 AsH[BM * 64];
  __shared__ bf16 AsL[BM * 64];
  __shared__ bf16 BsH[BN * 64];
  __shared__ bf16 BsL[BN * 64];
  int tid = threadIdx.x;
  int lane = tid & 63, wid = tid >> 6;
  int wr = wid >> 1, wc = wid & 1;
  int row0 = blockIdx.x * BM, col0 = blockIdx.y * BN;
  int l15 = lane & 15, l4 = lane >> 4;
  f32x4 acc[4][4] = {};
  for (int k0 = 0; k0 < 128; k0 += 64) {
    __syncthreads();
    #pragma unroll
    for (int it = 0; it < 4; ++it) {
      int chunk = it * 256 + tid;
      int r = chunk >> 3;
      int clog = (chunk & 7) ^ (r & 7);
      size_t goff = (size_t)(row0 + r) * 128 + k0 + clog * 8;
      gload_lds16(AH + goff, &AsH[chunk * 8]);
      gload_lds16(AL + goff, &AsL[chunk * 8]);
      size_t woff = (size_t)(col0 + r) * 128 + k0 + clog * 8;
      gload_lds16(WH + woff, &BsH[chunk * 8]);
      gload_lds16(WL + woff, &BsL[chunk * 8]);
    }
    __syncthreads();
    #pragma unroll
    for (int kk = 0; kk < 2; ++kk) {
      bf16x8 afh[4], afl[4], bfh[4], bfl[4];
      #pragma unroll
      for (int u = 0; u < 4; ++u) {
        int r = wr * 64 + u * 16 + l15;
        int csw = (kk * 4 + l4) ^ (r & 7);
        afh[u] = *(const bf16x8*)&AsH[r * 64 + csw * 8];
        afl[u] = *(const bf16x8*)&AsL[r * 64 + csw * 8];
      }
      #pragma unroll
      for (int v = 0; v < 4; ++v) {
        int r = wc * 64 + v * 16 + l15;
        int csw = (kk * 4 + l4) ^ (r & 7);
        bfh[v] = *(const bf16x8*)&BsH[r * 64 + csw * 8];
        bfl[v] = *(const bf16x8*)&BsL[r * 64 + csw * 8];
      }
      #pragma unroll
      for (int u = 0; u < 4; ++u)
        #pragma unroll
        for (int v = 0; v < 4; ++v) {
          acc[u][v] = __builtin_amdgcn_mfma_f32_16x16x32_bf16(afh[u], bfh[v], acc[u][v], 0, 0, 0);
          acc[u][v] = __builtin_amdgcn_mfma_f32_16x16x32_bf16(afl[u], bfh[v], acc[u][v], 0, 0, 0);
          acc[u][v] = __builtin_amdgcn_mfma_f32_16x16x32_bf16(afh[u], bfl[v], acc[u][v], 0, 0, 0);
        }
    }
  }
  bool isgate = (col0 >= 256);
  #pragma unroll
  for (int u = 0; u < 4; ++u) {
    int rbase = row0 + wr * 64 + u * 16 + l4 * 4;
    #pragma unroll
    for (int v = 0; v < 4; ++v) {
      int col = col0 + wc * 64 + v * 16 + l15;
      #pragma unroll
      for (int q = 0; q < 4; ++q) {
        float val = acc[u][v][q];
        if (!isgate) {
          hzx[(size_t)(rbase + q) * 256 + col] = val;
        } else {
          float s = val / (1.0f + __expf(-val));
          gate_f[(size_t)(rbase + q) * 256 + (col - 256)] = s;
        }
      }
    }
  }
}

// ================= x_proj (32x64, K=256): fused conv+silu staging, writes hs(bf162) + xp + dt =================
__global__ __launch_bounds__(256) void xproj_dt_kernel(const float* __restrict__ hzx,
                                                       const float* __restrict__ cw,
                                                       const float* __restrict__ cb,
                                                       const bf16* __restrict__ WH,
                                                       const bf16* __restrict__ WL,
                                                       const float* __restrict__ Wdt,
                                                       const float* __restrict__ bdt,
                                                       __hip_bfloat162* __restrict__ hs_p,
                                                       float* __restrict__ xp,
                                                       float* __restrict__ dtb) {
  __shared__ bf16 AsH[32 * 64];
  __shared__ bf16 AsL[32 * 64];
  __shared__ bf16 BsH[64 * 64];
  __shared__ bf16 BsL[64 * 64];
  __shared__ float xq[32][8];
  int tid = threadIdx.x;
  int lane = tid & 63, wid = tid >> 6;
  int wr = wid >> 1, wc = wid & 1;   // wave tile 16x32
  int row0 = blockIdx.x * 32;
  int l15 = lane & 15, l4 = lane >> 4;
  int r = tid >> 3, cslot = tid & 7;
  int tok = row0 + r;
  int lpos = tok & (LSEQ - 1);   // 32 | LSEQ, blocks never straddle sequences
  f32x4 acc[1][2] = {};
  for (int k0 = 0; k0 < 256; k0 += 64) {
    __syncthreads();
    {
      int kb = k0 + ((cslot ^ (r & 7)) << 3);
      const float* hp = &hzx[(size_t)tok * 256 + kb];
      float x3[8], x2[8], x1[8], x0[8];
      *(float4*)&x3[0] = *(const float4*)(hp);
      *(float4*)&x3[4] = *(const float4*)(hp + 4);
      if (lpos >= 1) { *(float4*)&x2[0] = *(const float4*)(hp - 256); *(float4*)&x2[4] = *(const float4*)(hp - 252); }
      else { *(float4*)&x2[0] = make_float4(0,0,0,0); *(float4*)&x2[4] = make_float4(0,0,0,0); }
      if (lpos >= 2) { *(float4*)&x1[0] = *(const float4*)(hp - 512); *(float4*)&x1[4] = *(const float4*)(hp - 508); }
      else { *(float4*)&x1[0] = make_float4(0,0,0,0); *(float4*)&x1[4] = make_float4(0,0,0,0); }
      if (lpos >= 3) { *(float4*)&x0[0] = *(const float4*)(hp - 768); *(float4*)&x0[4] = *(const float4*)(hp - 764); }
      else { *(float4*)&x0[0] = make_float4(0,0,0,0); *(float4*)&x0[4] = make_float4(0,0,0,0); }
      bf16 tH[8], tL[8];
      __hip_bfloat162 pk[8];
      #pragma unroll
      for (int j = 0; j < 8; ++j) {
        float4 w = *(const float4*)&cw[(kb + j) * 4];
        float s = cb[kb + j];
        s = fmaf(x0[j], w.x, s);
        s = fmaf(x1[j], w.y, s);
        s = fmaf(x2[j], w.z, s);
        s = fmaf(x3[j], w.w, s);
        s = s / (1.0f + __expf(-s));
        split_bf16(s, tH[j], tL[j]);
        pk[j].x = tH[j]; pk[j].y = tL[j];
      }
      *(bf16x8*)&AsH[tid * 8] = *(const bf16x8*)tH;
      *(bf16x8*)&AsL[tid * 8] = *(const bf16x8*)tL;
      *(float4*)&hs_p[(size_t)tok * 256 + kb]     = *(const float4*)&pk[0];
      *(float4*)&hs_p[(size_t)tok * 256 + kb + 4] = *(const float4*)&pk[4];
    }
    #pragma unroll
    for (int it = 0; it < 2; ++it) {
      int chunk = it * 256 + tid;
      int rr = chunk >> 3;
      int clog = (chunk & 7) ^ (rr & 7);
      size_t goff = (size_t)rr * 256 + k0 + clog * 8;
      gload_lds16(WH + goff, &BsH[chunk * 8]);
      gload_lds16(WL + goff, &BsL[chunk * 8]);
    }
    __syncthreads();
    #pragma unroll
    for (int kk = 0; kk < 2; ++kk) {
      bf16x8 afh, afl, bfh[2], bfl[2];
      {
        int rr = wr * 16 + l15;
        int csw = (kk * 4 + l4) ^ (rr & 7);
        afh = *(const bf16x8*)&AsH[rr * 64 + csw * 8];
        afl = *(const bf16x8*)&AsL[rr * 64 + csw * 8];
      }
      #pragma unroll
      for (int v = 0; v < 2; ++v) {
        int rr = wc * 32 + v * 16 + l15;
        int csw = (kk * 4 + l4) ^ (rr & 7);
        bfh[v] = *(const bf16x8*)&BsH[rr * 64 + csw * 8];
        bfl[v] = *(const bf16x8*)&BsL[rr * 64 + csw * 8];
      }
      #pragma unroll
      for (int v = 0; v < 2; ++v) {
        acc[0][v] = __builtin_amdgcn_mfma_f32_16x16x32_bf16(afh, bfh[v], acc[0][v], 0, 0, 0);
        acc[0][v] = __builtin_amdgcn_mfma_f32_16x16x32_bf16(afl, bfh[v], acc[0][v], 0, 0, 0);
        acc[0][v] = __builtin_amdgcn_mfma_f32_16x16x32_bf16(afh, bfl[v], acc[0][v], 0, 0, 0);
      }
    }
  }
  {
    int rbase = wr * 16 + l4 * 4;
    #pragma unroll
    for (int v = 0; v < 2; ++v) {
      int col = wc * 32 + v * 16 + l15;
      #pragma unroll
      for (int q = 0; q < 4; ++q) {
        float val = acc[0][v][q];
        xp[(size_t)(row0 + rbase + q) * 64 + col] = val;
        if (col < 8) xq[rbase + q][col] = val;
      }
    }
  }
  __syncthreads();
  {
    int i = tid;
    const float* wr8 = Wdt + i * 8;
    float w0 = wr8[0], w1 = wr8[1], w2 = wr8[2], w3 = wr8[3];
    float w4 = wr8[4], w5 = wr8[5], w6 = wr8[6], w7 = wr8[7];
    float bv = bdt[i];
    #pragma unroll 4
    for (int tt = 0; tt < 32; ++tt) {
      const float* q = xq[tt];
      float s = bv;
      s = fmaf(q[0], w0, s); s = fmaf(q[1], w1, s);
      s = fmaf(q[2], w2, s); s = fmaf(q[3], w3, s);
      s = fmaf(q[4], w4, s); s = fmaf(q[5], w5, s);
      s = fmaf(q[6], w6, s); s = fmaf(q[7], w7, s);
      float sp = (s > 20.0f) ? s : log1pf(__expf(s));
      dtb[(size_t)(row0 + tt) * 256 + i] = sp;
    }
  }
}

// ================= out_proj (32x128, K=256) + residual + fused next-layer RMSNorm =================
__global__ __launch_bounds__(256) void outproj_norm_kernel(const bf16* __restrict__ AH,
                                                           const bf16* __restrict__ AL,
                                                           const bf16* __restrict__ WH,
                                                           const bf16* __restrict__ WL,
                                                           const float* __restrict__ nw,
                                                           float* __restrict__ Ch,
                                                           bf16* __restrict__ hn_h,
                                                           bf16* __restrict__ hn_l) {
  constexpr int BM = 32, BN = 128;
  __shared__ bf16 AsH[BM * 64];
  __shared__ bf16 AsL[BM * 64];
  __shared__ bf16 BsH[BN * 64];
  __shared__ bf16 BsL[BN * 64];
  __shared__ float ssq[32][2];
  int tid = threadIdx.x;
  int lane = tid & 63, wid = tid >> 6;
  int wr = wid >> 1, wc = wid & 1;    // wave tile 16x64
  int row0 = blockIdx.x * BM;
  int l15 = lane & 15, l4 = lane >> 4;
  f32x4 acc[1][4] = {};
  for (int k0 = 0; k0 < 256; k0 += 64) {
    __syncthreads();
    {
      int chunk = tid;
      int r = chunk >> 3;
      int clog = (chunk & 7) ^ (r & 7);
      size_t goff = (size_t)(row0 + r) * 256 + k0 + clog * 8;
      gload_lds16(AH + goff, &AsH[chunk * 8]);
      gload_lds16(AL + goff, &AsL[chunk * 8]);
    }
    #pragma unroll
    for (int it = 0; it < 4; ++it) {
      int chunk = it * 256 + tid;
      int r = chunk >> 3;
      int clog = (chunk & 7) ^ (r & 7);
      size_t goff = (size_t)r * 256 + k0 + clog * 8;
      gload_lds16(WH + goff, &BsH[chunk * 8]);
      gload_lds16(WL + goff, &BsL[chunk * 8]);
    }
    __syncthreads();
    #pragma unroll
    for (int kk = 0; kk < 2; ++kk) {
      bf16x8 afh, afl, bfh[4], bfl[4];
      {
        int r = wr * 16 + l15;
        int csw = (kk * 4 + l4) ^ (r & 7);
        afh = *(const bf16x8*)&AsH[r * 64 + csw * 8];
        afl = *(const bf16x8*)&AsL[r * 64 + csw * 8];
      }
      #pragma unroll
      for (int v = 0; v < 4; ++v) {
        int r = wc * 64 + v * 16 + l15;
        int csw = (kk * 4 + l4) ^ (r & 7);
        bfh[v] = *(const bf16x8*)&BsH[r * 64 + csw * 8];
        bfl[v] = *(const bf16x8*)&BsL[r * 64 + csw * 8];
      }
      #pragma unroll
      for (int v = 0; v < 4; ++v) {
        acc[0][v] = __builtin_amdgcn_mfma_f32_16x16x32_bf16(afh, bfh[v], acc[0][v], 0, 0, 0);
        acc[0][v] = __builtin_amdgcn_mfma_f32_16x16x32_bf16(afl, bfh[v], acc[0][v], 0, 0, 0);
        acc[0][v] = __builtin_amdgcn_mfma_f32_16x16x32_bf16(afh, bfl[v], acc[0][v], 0, 0, 0);
      }
    }
  }
  int rloc = wr * 16 + l4 * 4;
  float vals[4][4];   // [q][v]
  #pragma unroll
  for (int v = 0; v < 4; ++v) {
    int col = wc * 64 + v * 16 + l15;
    #pragma unroll
    for (int q = 0; q < 4; ++q) {
      size_t off = (size_t)(row0 + rloc + q) * 128 + col;
      float val = acc[0][v][q] + Ch[off];
      vals[q][v] = val;
      Ch[off] = val;
    }
  }
  #pragma unroll
  for (int q = 0; q < 4; ++q) {
    float ss = vals[q][0] * vals[q][0] + vals[q][1] * vals[q][1]
             + vals[q][2] * vals[q][2] + vals[q][3] * vals[q][3];
    ss += __shfl_xor(ss, 1, 16);
    ss += __shfl_xor(ss, 2, 16);
    ss += __shfl_xor(ss, 4, 16);
    ss += __shfl_xor(ss, 8, 16);
    if (l15 == 0) ssq[rloc + q][wc] = ss;
  }
  __syncthreads();
  #pragma unroll
  for (int q = 0; q < 4; ++q) {
    float rstd = rsqrtf((ssq[rloc + q][0] + ssq[rloc + q][1]) * (1.0f / 128.0f) + 1e-5f);
    #pragma unroll
    for (int v = 0; v < 4; ++v) {
      int col = wc * 64 + v * 16 + l15;
      float o = vals[q][v] * rstd * nw[col];
      bf16 hh, ll;
      split_bf16(o, hh, ll);
      size_t off = (size_t)(row0 + rloc + q) * 128 + col;
      hn_h[off] = hh;
      hn_l[off] = ll;
    }
  }
}

// ================= chunked scan, lane-per-channel =================
// phase A: per-chunk (P,S).  grid (8, NCH), block 256
__global__ __launch_bounds__(256) void scanA_kernel(const float* __restrict__ dtb,
                                                    const __hip_bfloat162* __restrict__ hs_p,
                                                    const float* __restrict__ xp,
                                                    const float* __restrict__ A_log,
                                                    float* __restrict__ Pb,
                                                    float* __restrict__ Sb) {
  int b = blockIdx.x, c = blockIdx.y, i = threadIdx.x;
  float A[16];
  {
    const float4* ap = (const float4*)&A_log[i * 16];
    #pragma unroll
    for (int q = 0; q < 4; ++q) {
      float4 a = ap[q];
      A[q * 4 + 0] = -__expf(a.x); A[q * 4 + 1] = -__expf(a.y);
      A[q * 4 + 2] = -__expf(a.z); A[q * 4 + 3] = -__expf(a.w);
    }
  }
  float P[16], S[16];
  #pragma unroll
  for (int n = 0; n < 16; ++n) { P[n] = 1.0f; S[n] = 0.0f; }
  int t0 = b * LSEQ + c * CHL;
  for (int l = 0; l < CHL; ++l) {
    size_t t = t0 + l;
    float dtv = dtb[t * 256 + i];
    __hip_bfloat162 hp = hs_p[t * 256 + i];
    float hsv = __bfloat162float(hp.x) + __bfloat162float(hp.y);
    float dh = dtv * hsv;
    float Bv[16];
    #pragma unroll
    for (int q = 0; q < 4; ++q) {
      float4 bv = *(const float4*)&xp[t * 64 + 8 + q * 4];
      Bv[q * 4 + 0] = bv.x; Bv[q * 4 + 1] = bv.y; Bv[q * 4 + 2] = bv.z; Bv[q * 4 + 3] = bv.w;
    }
    #pragma unroll
    for (int n = 0; n < 16; ++n) {
      float e = __expf(dtv * A[n]);
      P[n] *= e;
      S[n] = fmaf(S[n], e, dh * Bv[n]);
    }
  }
  size_t base = ((size_t)(b * NCH + c) << 12) + i * 16;
  #pragma unroll
  for (int q = 0; q < 4; ++q) {
    *(float4*)&Pb[base + q * 4] = make_float4(P[q * 4], P[q * 4 + 1], P[q * 4 + 2], P[q * 4 + 3]);
    *(float4*)&Sb[base + q * 4] = make_float4(S[q * 4], S[q * 4 + 1], S[q * 4 + 2], S[q * 4 + 3]);
  }
}

// phase B: sequential prefix over chunks -> initial states. 32768 threads.
__global__ __launch_bounds__(256) void scanB_kernel(const float* __restrict__ Pb,
                                                    const float* __restrict__ Sb,
                                                    float* __restrict__ Ib) {
  int g = blockIdx.x * 256 + threadIdx.x;   // b*4096 + i*16 + n
  int b = g >> 12, rem = g & 4095;
  float s = 0.0f;
  for (int cc = 0; cc < NCH; ++cc) {
    size_t off = ((size_t)(b * NCH + cc) << 12) + rem;
    Ib[off] = s;
    s = fmaf(s, Pb[off], Sb[off]);
  }
}

// phase C: replay with initial state, emit y = (sum_n state*C + hs*D) * gate
__global__ __launch_bounds__(256) void scanC_kernel(const float* __restrict__ dtb,
                                                    const __hip_bfloat162* __restrict__ hs_p,
                                                    const float* __restrict__ xp,
                                                    const float* __restrict__ A_log,
                                                    const float* __restrict__ Dp,
                                                    const float* __restrict__ gate_f,
                                                    const float* __restrict__ Ib,
                                                    bf16* __restrict__ y_h,
                                                    bf16* __restrict__ y_l) {
  int b = blockIdx.x, c = blockIdx.y, i = threadIdx.x;
  float A[16];
  {
    const float4* ap = (const float4*)&A_log[i * 16];
    #pragma unroll
    for (int q = 0; q < 4; ++q) {
      float4 a = ap[q];
      A[q * 4 + 0] = -__expf(a.x); A[q * 4 + 1] = -__expf(a.y);
      A[q * 4 + 2] = -__expf(a.z); A[q * 4 + 3] = -__expf(a.w);
    }
  }
  float st[16];
  {
    size_t base = ((size_t)(b * NCH + c) << 12) + i * 16;
    #pragma unroll
    for (int q = 0; q < 4; ++q) {
      float4 s4 = *(const float4*)&Ib[base + q * 4];
      st[q * 4 + 0] = s4.x; st[q * 4 + 1] = s4.y; st[q * 4 + 2] = s4.z; st[q * 4 + 3] = s4.w;
    }
  }
  float Dv = Dp[i];
  int t0 = b * LSEQ + c * CHL;
  for (int l = 0; l < CHL; ++l) {
    size_t t = t0 + l;
    float dtv = dtb[t * 256 + i];
    __hip_bfloat162 hp = hs_p[t * 256 + i];
    float hsv = __bfloat162float(hp.x) + __bfloat162float(hp.y);
    float dh = dtv * hsv;
    float Bv[16], Cv[16];
    #pragma unroll
    for (int q = 0; q < 4; ++q) {
      float4 bv = *(const float4*)&xp[t * 64 + 8 + q * 4];
      Bv[q * 4 + 0] = bv.x; Bv[q * 4 + 1] = bv.y; Bv[q * 4 + 2] = bv.z; Bv[q * 4 + 3] = bv.w;
      float4 cv = *(const float4*)&xp[t * 64 + 24 + q * 4];
      Cv[q * 4 + 0] = cv.x; Cv[q * 4 + 1] = cv.y; Cv[q * 4 + 2] = cv.z; Cv[q * 4 + 3] = cv.w;
    }
    float y0 = 0.f, y1 = 0.f, y2 = 0.f, y3 = 0.f;
    #pragma unroll
    for (int q = 0; q < 4; ++q) {
      float e0 = __expf(dtv * A[q * 4 + 0]);
      float e1 = __expf(dtv * A[q * 4 + 1]);
      float e2 = __expf(dtv * A[q * 4 + 2]);
      float e3 = __expf(dtv * A[q * 4 + 3]);
      st[q * 4 + 0] = fmaf(st[q * 4 + 0], e0, dh * Bv[q * 4 + 0]);
      st[q * 4 + 1] = fmaf(st[q * 4 + 1], e1, dh * Bv[q * 4 + 1]);
      st[q * 4 + 2] = fmaf(st[q * 4 + 2], e2, dh * Bv[q * 4 + 2]);
      st[q * 4 + 3] = fmaf(st[q * 4 + 3], e3, dh * Bv[q * 4 + 3]);
      y0 = fmaf(st[q * 4 + 0], Cv[q * 4 + 0], y0);
      y1 = fmaf(st[q * 4 + 1], Cv[q * 4 + 1], y1);
      y2 = fmaf(st[q * 4 + 2], Cv[q * 4 + 2], y2);
      y3 = fmaf(st[q * 4 + 3], Cv[q * 4 + 3], y3);
    }
    float y = ((y0 + y1) + (y2 + y3)) + hsv * Dv;
    float g = gate_f[t * 256 + i];
    float val = y * g;
    bf16 hh, ll;
    split_bf16(val, hh, ll);
    y_h[t * 256 + i] = hh;
    y_l[t * 256 + i] = ll;
  }
}

extern "C" void kernel_launch(void* const* d_in, const int* in_sizes, int n_in,
                              void* d_out, int out_size, void* d_ws, size_t ws_size,
                              hipStream_t stream) {
  const int* x           = (const int*)d_in[0];
  const float* embed     = (const float*)d_in[1];
  const float* in_proj_w = (const float*)d_in[2];
  const float* conv_w    = (const float*)d_in[3];
  const float* conv_b    = (const float*)d_in[4];
  const float* x_proj_w  = (const float*)d_in[5];
  const float* dt_proj_w = (const float*)d_in[6];
  const float* dt_proj_b = (const float*)d_in[7];
  const float* A_log     = (const float*)d_in[8];
  const float* Dp        = (const float*)d_in[9];
  const float* out_proj_w= (const float*)d_in[10];
  const float* norm_w    = (const float*)d_in[11];
  const float* norm_f_w  = (const float*)d_in[12];
  const float* head_w    = (const float*)d_in[13];
  const float* head_b    = (const float*)d_in[14];

  float* out = (float*)d_out;
  float* ws  = (float*)d_ws;

  // ---- d_out scratch map (f32 word offsets; budget 33,554,432) ----
  // hzx is DEAD after xproj_dt (scans read hs_p) -> Pb/Sb alias hzx's region.
  float* hzx     = out;                          //  4,194,304 (T*256 f32)
  float* Pb      = out;                          //  2,097,152 (8*NCH*4096) [aliases hzx]
  float* Sb      = out + 2097152;                //  2,097,152              [aliases hzx]
  float* gate_f  = out + 4194304;                //  4,194,304 (T*256 f32)
  __hip_bfloat162* hs_p = (__hip_bfloat162*)(out + 8388608);   // 4,194,304 w (T*256 bf162)
  float* dtb     = out + 12582912;               //  4,194,304 (T*256 f32)
  float* xp      = out + 16777216;               //  1,048,576 (T*64 f32)
  bf16*  y_h     = (bf16*)(out + 17825792);      //  2,097,152 w
  bf16*  y_l     = (bf16*)(out + 19922944);      //  2,097,152 w
  float* h       = out + 22020096;               //  2,097,152 (T*128 residual)
  bf16*  w_in_h  = (bf16*)(out + 24117248);      //  1,048,576 w
  bf16*  w_in_l  = (bf16*)(out + 25165824);      //  1,048,576 w
  bf16*  w_x_h   = (bf16*)(out + 26214400);      //    262,144 w (padded 64 rows)
  bf16*  w_x_l   = (bf16*)(out + 26476544);
  bf16*  w_out_h = (bf16*)(out + 26738688);      //    524,288 w
  bf16*  w_out_l = (bf16*)(out + 27262976);
  float* Ib      = out + 27787264;               //  2,097,152 -> ends 29,884,416

  // ---- ws scratch (~9.4 MB) — live through the head GEMM ----
  bf16* hn_h     = (bf16*)ws;                    // T*128 bf16
  bf16* hn_l     = (bf16*)(ws + 1048576);
  bf16* w_head_h = (bf16*)(ws + 2097152);        // 2048*128 bf16
  bf16* w_head_l = (bf16*)(ws + 2228224);

  cast_split_kernel<<<8192, 256, 0, stream>>>(in_proj_w, w_in_h, w_in_l, 2097152);
  cast_xproj_kernel<<<2048, 256, 0, stream>>>(x_proj_w, w_x_h, w_x_l);
  cast_split_kernel<<<4096, 256, 0, stream>>>(out_proj_w, w_out_h, w_out_l, 1048576);
  cast_split_kernel<<<1024, 256, 0, stream>>>(head_w, w_head_h, w_head_l, 262144);

  embed_kernel<<<8192, 256, 0, stream>>>(x, embed, h);
  rmsnorm_split_kernel<<<4096, 256, 0, stream>>>(h, norm_w, hn_h, hn_l);

  for (int l = 0; l < 32; ++l) {
    inproj_kernel<<<dim3(128, 4), 256, 0, stream>>>(
        hn_h, hn_l, w_in_h + (size_t)l * 512 * 128, w_in_l + (size_t)l * 512 * 128,
        hzx, gate_f);
    xproj_dt_kernel<<<512, 256, 0, stream>>>(
        hzx, conv_w + l * 1024, conv_b + l * 256,
        w_x_h + (size_t)l * 64 * 256, w_x_l + (size_t)l * 64 * 256,
        dt_proj_w + l * 2048, dt_proj_b + l * 256, hs_p, xp, dtb);
    scanA_kernel<<<dim3(8, NCH), 256, 0, stream>>>(
        dtb, hs_p, xp, A_log + l * 4096, Pb, Sb);
    scanB_kernel<<<128, 256, 0, stream>>>(Pb, Sb, Ib);
    scanC_kernel<<<dim3(8, NCH), 256, 0, stream>>>(
        dtb, hs_p, xp, A_log + l * 4096, Dp + l * 256, gate_f, Ib, y_h, y_l);
    const float* nwnext = (l < 31) ? (norm_w + (l + 1) * 128) : norm_f_w;
    outproj_norm_kernel<<<512, 256, 0, stream>>>(
        y_h, y_l, w_out_h + (size_t)l * 128 * 256, w_out_l + (size_t)l * 128 * 256,
        nwnext, h, hn_h, hn_l);
  }

  mfma_gemm<128, 128, 2, 2, 2><<<dim3(128, 16), 256, 0, stream>>>(
      hn_h, hn_l, w_head_h, w_head_l, out, head_b, 2048, 128);
}

// Round 15
// 3315.832 us; speedup vs baseline: 3.9640x; 1.0725x over previous
//
#include <hip/hip_runtime.h>
#include <hip/hip_bf16.h>

#define LSEQ 2048
#define NCH 64          // chunks per sequence
#define CHL 32          // chunk length (NCH*CHL == LSEQ)

typedef __attribute__((ext_vector_type(8))) short bf16x8;
typedef __attribute__((ext_vector_type(4))) float f32x4;
typedef __hip_bfloat16 bf16;

__device__ __forceinline__ void gload_lds16(const void* g, void* l) {
  __builtin_amdgcn_global_load_lds(
      (const __attribute__((address_space(1))) void*)g,
      (__attribute__((address_space(3))) void*)l, 16, 0, 0);
}

__device__ __forceinline__ void split_bf16(float v, bf16& h, bf16& l) {
  h = __float2bfloat16(v);
  l = __float2bfloat16(v - __bfloat162float(h));
}

// ---------------- embed ----------------
__global__ __launch_bounds__(256) void embed_kernel(const int* __restrict__ x,
                                                    const float* __restrict__ emb,
                                                    float* __restrict__ h) {
  int idx = blockIdx.x * 256 + threadIdx.x;   // T*128
  int t = idx >> 7;
  int d = idx & 127;
  h[idx] = emb[(size_t)x[t] * 128 + d];
}

// ---------------- weight casts (hi/lo split) ----------------
__global__ __launch_bounds__(256) void cast_split_kernel(const float* __restrict__ src,
                                                         bf16* __restrict__ hi,
                                                         bf16* __restrict__ lo, int n) {
  int i = blockIdx.x * 256 + threadIdx.x;
  if (i < n) { bf16 h, l; split_bf16(src[i], h, l); hi[i] = h; lo[i] = l; }
}

// x_proj: src [32][40][256] -> dst [32][64][256], rows 40..63 zero
__global__ __launch_bounds__(256) void cast_xproj_kernel(const float* __restrict__ src,
                                                         bf16* __restrict__ hi,
                                                         bf16* __restrict__ lo) {
  int i = blockIdx.x * 256 + threadIdx.x;   // 32*64*256
  int k = i & 255, n = (i >> 8) & 63, l = i >> 14;
  float v = (n < 40) ? src[((size_t)l * 40 + n) * 256 + k] : 0.f;
  bf16 h, lw; split_bf16(v, h, lw);
  hi[i] = h; lo[i] = lw;
}

// ---------------- rmsnorm -> bf16 hi/lo (layer-0 input only) ----------------
__global__ __launch_bounds__(256) void rmsnorm_split_kernel(const float* __restrict__ hin,
                                                            const float* __restrict__ w,
                                                            bf16* __restrict__ hout_h,
                                                            bf16* __restrict__ hout_l) {
  int row = blockIdx.x * 4 + (threadIdx.x >> 6);
  int lane = threadIdx.x & 63;
  float2 v = *(const float2*)&hin[(size_t)row * 128 + lane * 2];
  float ss = v.x * v.x + v.y * v.y;
  #pragma unroll
  for (int m = 1; m < 64; m <<= 1) ss += __shfl_xor(ss, m);
  float rstd = rsqrtf(ss * (1.0f / 128.0f) + 1e-5f);
  float2 wv = *(const float2*)&w[lane * 2];
  float o0 = v.x * rstd * wv.x, o1 = v.y * rstd * wv.y;
  __hip_bfloat162 ph, pl;
  bf16 hh, ll;
  split_bf16(o0, hh, ll); ph.x = hh; pl.x = ll;
  split_bf16(o1, hh, ll); ph.y = hh; pl.y = ll;
  *(__hip_bfloat162*)&hout_h[(size_t)row * 128 + lane * 2] = ph;
  *(__hip_bfloat162*)&hout_l[(size_t)row * 128 + lane * 2] = pl;
}

// ================= generic split-bf16 MFMA GEMM (head) =================
template <int BM, int BN, int WR, int WC, int EPI>
__global__ __launch_bounds__(256) void mfma_gemm(const bf16* __restrict__ AH,
                                                 const bf16* __restrict__ AL,
                                                 const bf16* __restrict__ WH,
                                                 const bf16* __restrict__ WL,
                                                 float* __restrict__ C,
                                                 const float* __restrict__ bias,
                                                 int Nc, int Kc) {
  constexpr int WTM = BM / WR, WTN = BN / WC;
  constexpr int U = WTM / 16, V = WTN / 16;
  __shared__ bf16 AsH[BM * 64];
  __shared__ bf16 AsL[BM * 64];
  __shared__ bf16 BsH[BN * 64];
  __shared__ bf16 BsL[BN * 64];
  int tid = threadIdx.x;
  int lane = tid & 63, wid = tid >> 6;
  int wr = wid / WC, wc = wid % WC;
  int row0 = blockIdx.x * BM, col0 = blockIdx.y * BN;
  int l15 = lane & 15, l4 = lane >> 4;
  f32x4 acc[U][V] = {};
  for (int k0 = 0; k0 < Kc; k0 += 64) {
    __syncthreads();
    #pragma unroll
    for (int it = 0; it < BM / 32; ++it) {
      int chunk = it * 256 + tid;
      int r = chunk >> 3;
      int clog = (chunk & 7) ^ (r & 7);
      size_t goff = (size_t)(row0 + r) * Kc + k0 + clog * 8;
      gload_lds16(AH + goff, &AsH[chunk * 8]);
      gload_lds16(AL + goff, &AsL[chunk * 8]);
    }
    #pragma unroll
    for (int it = 0; it < BN / 32; ++it) {
      int chunk = it * 256 + tid;
      int r = chunk >> 3;
      int clog = (chunk & 7) ^ (r & 7);
      size_t goff = (size_t)(col0 + r) * Kc + k0 + clog * 8;
      gload_lds16(WH + goff, &BsH[chunk * 8]);
      gload_lds16(WL + goff, &BsL[chunk * 8]);
    }
    __syncthreads();
    #pragma unroll
    for (int kk = 0; kk < 2; ++kk) {
      bf16x8 afh[U], afl[U], bfh[V], bfl[V];
      #pragma unroll
      for (int u = 0; u < U; ++u) {
        int r = wr * WTM + u * 16 + l15;
        int csw = (kk * 4 + l4) ^ (r & 7);
        afh[u] = *(const bf16x8*)&AsH[r * 64 + csw * 8];
        afl[u] = *(const bf16x8*)&AsL[r * 64 + csw * 8];
      }
      #pragma unroll
      for (int v = 0; v < V; ++v) {
        int r = wc * WTN + v * 16 + l15;
        int csw = (kk * 4 + l4) ^ (r & 7);
        bfh[v] = *(const bf16x8*)&BsH[r * 64 + csw * 8];
        bfl[v] = *(const bf16x8*)&BsL[r * 64 + csw * 8];
      }
      #pragma unroll
      for (int u = 0; u < U; ++u)
        #pragma unroll
        for (int v = 0; v < V; ++v) {
          acc[u][v] = __builtin_amdgcn_mfma_f32_16x16x32_bf16(afh[u], bfh[v], acc[u][v], 0, 0, 0);
          acc[u][v] = __builtin_amdgcn_mfma_f32_16x16x32_bf16(afl[u], bfh[v], acc[u][v], 0, 0, 0);
          acc[u][v] = __builtin_amdgcn_mfma_f32_16x16x32_bf16(afh[u], bfl[v], acc[u][v], 0, 0, 0);
        }
    }
  }
  #pragma unroll
  for (int u = 0; u < U; ++u) {
    int rbase = row0 + wr * WTM + u * 16 + l4 * 4;
    #pragma unroll
    for (int v = 0; v < V; ++v) {
      int col = col0 + wc * WTN + v * 16 + l15;
      #pragma unroll
      for (int q = 0; q < 4; ++q) {
        size_t off = (size_t)(rbase + q) * Nc + col;
        float val = acc[u][v][q];
        if (EPI == 2) val += bias[col];
        C[off] = val;
      }
    }
  }
}

// ================= in_proj (128x128, K=128): writes hzx(f32) / silu(gate)(f32) =================
__global__ __launch_bounds__(256) void inproj_kernel(const bf16* __restrict__ AH,
                                                     const bf16* __restrict__ AL,
                                                     const bf16* __restrict__ WH,
                                                     const bf16* __restrict__ WL,
                                                     float* __restrict__ hzx,
                                                     float* __restrict__ gate_f) {
  constexpr int BM = 128, BN = 128;
  __shared__ bf16 AsH[BM * 64];
  __shared__ bf16 AsL[BM * 64];
  __shared__ bf16 BsH[BN * 64];
  __shared__ bf16 BsL[BN * 64];
  int tid = threadIdx.x;
  int lane = tid & 63, wid = tid >> 6;
  int wr = wid >> 1, wc = wid & 1;
  int row0 = blockIdx.x * BM, col0 = blockIdx.y * BN;
  int l15 = lane & 15, l4 = lane >> 4;
  f32x4 acc[4][4] = {};
  for (int k0 = 0; k0 < 128; k0 += 64) {
    __syncthreads();
    #pragma unroll
    for (int it = 0; it < 4; ++it) {
      int chunk = it * 256 + tid;
      int r = chunk >> 3;
      int clog = (chunk & 7) ^ (r & 7);
      size_t goff = (size_t)(row0 + r) * 128 + k0 + clog * 8;
      gload_lds16(AH + goff, &AsH[chunk * 8]);
      gload_lds16(AL + goff, &AsL[chunk * 8]);
      size_t woff = (size_t)(col0 + r) * 128 + k0 + clog * 8;
      gload_lds16(WH + woff, &BsH[chunk * 8]);
      gload_lds16(WL + woff, &BsL[chunk * 8]);
    }
    __syncthreads();
    #pragma unroll
    for (int kk = 0; kk < 2; ++kk) {
      bf16x8 afh[4], afl[4], bfh[4], bfl[4];
      #pragma unroll
      for (int u = 0; u < 4; ++u) {
        int r = wr * 64 + u * 16 + l15;
        int csw = (kk * 4 + l4) ^ (r & 7);
        afh[u] = *(const bf16x8*)&AsH[r * 64 + csw * 8];
        afl[u] = *(const bf16x8*)&AsL[r * 64 + csw * 8];
      }
      #pragma unroll
      for (int v = 0; v < 4; ++v) {
        int r = wc * 64 + v * 16 + l15;
        int csw = (kk * 4 + l4) ^ (r & 7);
        bfh[v] = *(const bf16x8*)&BsH[r * 64 + csw * 8];
        bfl[v] = *(const bf16x8*)&BsL[r * 64 + csw * 8];
      }
      #pragma unroll
      for (int u = 0; u < 4; ++u)
        #pragma unroll
        for (int v = 0; v < 4; ++v) {
          acc[u][v] = __builtin_amdgcn_mfma_f32_16x16x32_bf16(afh[u], bfh[v], acc[u][v], 0, 0, 0);
          acc[u][v] = __builtin_amdgcn_mfma_f32_16x16x32_bf16(afl[u], bfh[v], acc[u][v], 0, 0, 0);
          acc[u][v] = __builtin_amdgcn_mfma_f32_16x16x32_bf16(afh[u], bfl[v], acc[u][v], 0, 0, 0);
        }
    }
  }
  bool isgate = (col0 >= 256);
  #pragma unroll
  for (int u = 0; u < 4; ++u) {
    int rbase = row0 + wr * 64 + u * 16 + l4 * 4;
    #pragma unroll
    for (int v = 0; v < 4; ++v) {
      int col = col0 + wc * 64 + v * 16 + l15;
      #pragma unroll
      for (int q = 0; q < 4; ++q) {
        float val = acc[u][v][q];
        if (!isgate) {
          hzx[(size_t)(rbase + q) * 256 + col] = val;
        } else {
          float s = val / (1.0f + __expf(-val));
          gate_f[(size_t)(rbase + q) * 256 + (col - 256)] = s;
        }
      }
    }
  }
}

// ================= x_proj (32x64, K=256) + conv/silu staging + dt + FUSED chunk-scan (phase A) ======
// Block bid covers tokens [bid*32, bid*32+32) == scan chunk (b = bid>>6, c = bid&63).
__global__ __launch_bounds__(256) void xproj_scan_kernel(const float* __restrict__ hzx,
                                                         const float* __restrict__ cw,
                                                         const float* __restrict__ cb,
                                                         const bf16* __restrict__ WH,
                                                         const bf16* __restrict__ WL,
                                                         const float* __restrict__ Wdt,
                                                         const float* __restrict__ bdt,
                                                         const float* __restrict__ A_log,
                                                         __hip_bfloat162* __restrict__ hs_p,
                                                         float* __restrict__ xp,
                                                         float* __restrict__ dtb,
                                                         float* __restrict__ Pb,
                                                         float* __restrict__ Sb) {
  __shared__ bf16 AsH[32 * 64];
  __shared__ bf16 AsL[32 * 64];
  __shared__ bf16 BsH[64 * 64];
  __shared__ bf16 BsL[64 * 64];
  __shared__ float xq[32][24];                 // xp cols 0..23 (dt inputs + B)
  __shared__ __hip_bfloat162 hs_lds[32][257];  // +1 pad: conflict-free
  int tid = threadIdx.x;
  int lane = tid & 63, wid = tid >> 6;
  int wr = wid >> 1, wc = wid & 1;   // wave tile 16x32
  int row0 = blockIdx.x * 32;
  int l15 = lane & 15, l4 = lane >> 4;
  int r = tid >> 3, cslot = tid & 7;
  int tok = row0 + r;
  int lpos = tok & (LSEQ - 1);   // 32 | LSEQ, blocks never straddle sequences
  f32x4 acc[1][2] = {};
  for (int k0 = 0; k0 < 256; k0 += 64) {
    __syncthreads();
    {
      int kb = k0 + ((cslot ^ (r & 7)) << 3);
      const float* hp = &hzx[(size_t)tok * 256 + kb];
      float x3[8], x2[8], x1[8], x0[8];
      *(float4*)&x3[0] = *(const float4*)(hp);
      *(float4*)&x3[4] = *(const float4*)(hp + 4);
      if (lpos >= 1) { *(float4*)&x2[0] = *(const float4*)(hp - 256); *(float4*)&x2[4] = *(const float4*)(hp - 252); }
      else { *(float4*)&x2[0] = make_float4(0,0,0,0); *(float4*)&x2[4] = make_float4(0,0,0,0); }
      if (lpos >= 2) { *(float4*)&x1[0] = *(const float4*)(hp - 512); *(float4*)&x1[4] = *(const float4*)(hp - 508); }
      else { *(float4*)&x1[0] = make_float4(0,0,0,0); *(float4*)&x1[4] = make_float4(0,0,0,0); }
      if (lpos >= 3) { *(float4*)&x0[0] = *(const float4*)(hp - 768); *(float4*)&x0[4] = *(const float4*)(hp - 764); }
      else { *(float4*)&x0[0] = make_float4(0,0,0,0); *(float4*)&x0[4] = make_float4(0,0,0,0); }
      bf16 tH[8], tL[8];
      __hip_bfloat162 pk[8];
      #pragma unroll
      for (int j = 0; j < 8; ++j) {
        float4 w = *(const float4*)&cw[(kb + j) * 4];
        float s = cb[kb + j];
        s = fmaf(x0[j], w.x, s);
        s = fmaf(x1[j], w.y, s);
        s = fmaf(x2[j], w.z, s);
        s = fmaf(x3[j], w.w, s);
        s = s / (1.0f + __expf(-s));
        split_bf16(s, tH[j], tL[j]);
        pk[j].x = tH[j]; pk[j].y = tL[j];
        hs_lds[r][kb + j] = pk[j];
      }
      *(bf16x8*)&AsH[tid * 8] = *(const bf16x8*)tH;
      *(bf16x8*)&AsL[tid * 8] = *(const bf16x8*)tL;
      *(float4*)&hs_p[(size_t)tok * 256 + kb]     = *(const float4*)&pk[0];
      *(float4*)&hs_p[(size_t)tok * 256 + kb + 4] = *(const float4*)&pk[4];
    }
    #pragma unroll
    for (int it = 0; it < 2; ++it) {
      int chunk = it * 256 + tid;
      int rr = chunk >> 3;
      int clog = (chunk & 7) ^ (rr & 7);
      size_t goff = (size_t)rr * 256 + k0 + clog * 8;
      gload_lds16(WH + goff, &BsH[chunk * 8]);
      gload_lds16(WL + goff, &BsL[chunk * 8]);
    }
    __syncthreads();
    #pragma unroll
    for (int kk = 0; kk < 2; ++kk) {
      bf16x8 afh, afl, bfh[2], bfl[2];
      {
        int rr = wr * 16 + l15;
        int csw = (kk * 4 + l4) ^ (rr & 7);
        afh = *(const bf16x8*)&AsH[rr * 64 + csw * 8];
        afl = *(const bf16x8*)&AsL[rr * 64 + csw * 8];
      }
      #pragma unroll
      for (int v = 0; v < 2; ++v) {
        int rr = wc * 32 + v * 16 + l15;
        int csw = (kk * 4 + l4) ^ (rr & 7);
        bfh[v] = *(const bf16x8*)&BsH[rr * 64 + csw * 8];
        bfl[v] = *(const bf16x8*)&BsL[rr * 64 + csw * 8];
      }
      #pragma unroll
      for (int v = 0; v < 2; ++v) {
        acc[0][v] = __builtin_amdgcn_mfma_f32_16x16x32_bf16(afh, bfh[v], acc[0][v], 0, 0, 0);
        acc[0][v] = __builtin_amdgcn_mfma_f32_16x16x32_bf16(afl, bfh[v], acc[0][v], 0, 0, 0);
        acc[0][v] = __builtin_amdgcn_mfma_f32_16x16x32_bf16(afh, bfl[v], acc[0][v], 0, 0, 0);
      }
    }
  }
  // epilogue: write xp; stash cols 0..23 into LDS
  {
    int rbase = wr * 16 + l4 * 4;
    #pragma unroll
    for (int v = 0; v < 2; ++v) {
      int col = wc * 32 + v * 16 + l15;
      #pragma unroll
      for (int q = 0; q < 4; ++q) {
        float val = acc[0][v][q];
        xp[(size_t)(row0 + rbase + q) * 64 + col] = val;
        if (col < 24) xq[rbase + q][col] = val;
      }
    }
  }
  __syncthreads();
  // dt + chunk-scan phase: thread i owns channel i, 16 states in registers
  {
    int i = tid;
    float A[16];
    {
      const float4* ap = (const float4*)&A_log[i * 16];
      #pragma unroll
      for (int q = 0; q < 4; ++q) {
        float4 a = ap[q];
        A[q * 4 + 0] = -__expf(a.x); A[q * 4 + 1] = -__expf(a.y);
        A[q * 4 + 2] = -__expf(a.z); A[q * 4 + 3] = -__expf(a.w);
      }
    }
    const float* wr8 = Wdt + i * 8;
    float w0 = wr8[0], w1 = wr8[1], w2 = wr8[2], w3 = wr8[3];
    float w4 = wr8[4], w5 = wr8[5], w6 = wr8[6], w7 = wr8[7];
    float bv = bdt[i];
    float P[16], S[16];
    #pragma unroll
    for (int n = 0; n < 16; ++n) { P[n] = 1.0f; S[n] = 0.0f; }
    for (int tt = 0; tt < 32; ++tt) {
      const float* q = xq[tt];
      float s = bv;
      s = fmaf(q[0], w0, s); s = fmaf(q[1], w1, s);
      s = fmaf(q[2], w2, s); s = fmaf(q[3], w3, s);
      s = fmaf(q[4], w4, s); s = fmaf(q[5], w5, s);
      s = fmaf(q[6], w6, s); s = fmaf(q[7], w7, s);
      float dtv = (s > 20.0f) ? s : log1pf(__expf(s));
      dtb[(size_t)(row0 + tt) * 256 + i] = dtv;
      __hip_bfloat162 hp = hs_lds[tt][i];
      float hsv = __bfloat162float(hp.x) + __bfloat162float(hp.y);
      float dh = dtv * hsv;
      #pragma unroll
      for (int n = 0; n < 16; ++n) {
        float e = __expf(dtv * A[n]);
        P[n] *= e;
        S[n] = fmaf(S[n], e, dh * q[8 + n]);
      }
    }
    size_t base = ((size_t)blockIdx.x << 12) + i * 16;
    #pragma unroll
    for (int qq = 0; qq < 4; ++qq) {
      *(float4*)&Pb[base + qq * 4] = make_float4(P[qq * 4], P[qq * 4 + 1], P[qq * 4 + 2], P[qq * 4 + 3]);
      *(float4*)&Sb[base + qq * 4] = make_float4(S[qq * 4], S[qq * 4 + 1], S[qq * 4 + 2], S[qq * 4 + 3]);
    }
  }
}

// ================= out_proj (32x128, K=256) + residual + fused next-layer RMSNorm =================
__global__ __launch_bounds__(256) void outproj_norm_kernel(const bf16* __restrict__ AH,
                                                           const bf16* __restrict__ AL,
                                                           const bf16* __restrict__ WH,
                                                           const bf16* __restrict__ WL,
                                                           const float* __restrict__ nw,
                                                           float* __restrict__ Ch,
                                                           bf16* __restrict__ hn_h,
                                                           bf16* __restrict__ hn_l) {
  constexpr int BM = 32, BN = 128;
  __shared__ bf16 AsH[BM * 64];
  __shared__ bf16 AsL[BM * 64];
  __shared__ bf16 BsH[BN * 64];
  __shared__ bf16 BsL[BN * 64];
  __shared__ float ssq[32][2];
  int tid = threadIdx.x;
  int lane = tid & 63, wid = tid >> 6;
  int wr = wid >> 1, wc = wid & 1;    // wave tile 16x64
  int row0 = blockIdx.x * BM;
  int l15 = lane & 15, l4 = lane >> 4;
  f32x4 acc[1][4] = {};
  for (int k0 = 0; k0 < 256; k0 += 64) {
    __syncthreads();
    {
      int chunk = tid;
      int r = chunk >> 3;
      int clog = (chunk & 7) ^ (r & 7);
      size_t goff = (size_t)(row0 + r) * 256 + k0 + clog * 8;
      gload_lds16(AH + goff, &AsH[chunk * 8]);
      gload_lds16(AL + goff, &AsL[chunk * 8]);
    }
    #pragma unroll
    for (int it = 0; it < 4; ++it) {
      int chunk = it * 256 + tid;
      int r = chunk >> 3;
      int clog = (chunk & 7) ^ (r & 7);
      size_t goff = (size_t)r * 256 + k0 + clog * 8;
      gload_lds16(WH + goff, &BsH[chunk * 8]);
      gload_lds16(WL + goff, &BsL[chunk * 8]);
    }
    __syncthreads();
    #pragma unroll
    for (int kk = 0; kk < 2; ++kk) {
      bf16x8 afh, afl, bfh[4], bfl[4];
      {
        int r = wr * 16 + l15;
        int csw = (kk * 4 + l4) ^ (r & 7);
        afh = *(const bf16x8*)&AsH[r * 64 + csw * 8];
        afl = *(const bf16x8*)&AsL[r * 64 + csw * 8];
      }
      #pragma unroll
      for (int v = 0; v < 4; ++v) {
        int r = wc * 64 + v * 16 + l15;
        int csw = (kk * 4 + l4) ^ (r & 7);
        bfh[v] = *(const bf16x8*)&BsH[r * 64 + csw * 8];
        bfl[v] = *(const bf16x8*)&BsL[r * 64 + csw * 8];
      }
      #pragma unroll
      for (int v = 0; v < 4; ++v) {
        acc[0][v] = __builtin_amdgcn_mfma_f32_16x16x32_bf16(afh, bfh[v], acc[0][v], 0, 0, 0);
        acc[0][v] = __builtin_amdgcn_mfma_f32_16x16x32_bf16(afl, bfh[v], acc[0][v], 0, 0, 0);
        acc[0][v] = __builtin_amdgcn_mfma_f32_16x16x32_bf16(afh, bfl[v], acc[0][v], 0, 0, 0);
      }
    }
  }
  int rloc = wr * 16 + l4 * 4;
  float vals[4][4];   // [q][v]
  #pragma unroll
  for (int v = 0; v < 4; ++v) {
    int col = wc * 64 + v * 16 + l15;
    #pragma unroll
    for (int q = 0; q < 4; ++q) {
      size_t off = (size_t)(row0 + rloc + q) * 128 + col;
      float val = acc[0][v][q] + Ch[off];
      vals[q][v] = val;
      Ch[off] = val;
    }
  }
  #pragma unroll
  for (int q = 0; q < 4; ++q) {
    float ss = vals[q][0] * vals[q][0] + vals[q][1] * vals[q][1]
             + vals[q][2] * vals[q][2] + vals[q][3] * vals[q][3];
    ss += __shfl_xor(ss, 1, 16);
    ss += __shfl_xor(ss, 2, 16);
    ss += __shfl_xor(ss, 4, 16);
    ss += __shfl_xor(ss, 8, 16);
    if (l15 == 0) ssq[rloc + q][wc] = ss;
  }
  __syncthreads();
  #pragma unroll
  for (int q = 0; q < 4; ++q) {
    float rstd = rsqrtf((ssq[rloc + q][0] + ssq[rloc + q][1]) * (1.0f / 128.0f) + 1e-5f);
    #pragma unroll
    for (int v = 0; v < 4; ++v) {
      int col = wc * 64 + v * 16 + l15;
      float o = vals[q][v] * rstd * nw[col];
      bf16 hh, ll;
      split_bf16(o, hh, ll);
      size_t off = (size_t)(row0 + rloc + q) * 128 + col;
      hn_h[off] = hh;
      hn_l[off] = ll;
    }
  }
}

// phase B: sequential prefix over chunks -> initial states. 32768 threads.
__global__ __launch_bounds__(256) void scanB_kernel(const float* __restrict__ Pb,
                                                    const float* __restrict__ Sb,
                                                    float* __restrict__ Ib) {
  int g = blockIdx.x * 256 + threadIdx.x;   // b*4096 + i*16 + n
  int b = g >> 12, rem = g & 4095;
  float s = 0.0f;
  for (int cc = 0; cc < NCH; ++cc) {
    size_t off = ((size_t)(b * NCH + cc) << 12) + rem;
    Ib[off] = s;
    s = fmaf(s, Pb[off], Sb[off]);
  }
}

// phase C: replay with initial state, emit y = (sum_n state*C + hs*D) * gate
__global__ __launch_bounds__(256) void scanC_kernel(const float* __restrict__ dtb,
                                                    const __hip_bfloat162* __restrict__ hs_p,
                                                    const float* __restrict__ xp,
                                                    const float* __restrict__ A_log,
                                                    const float* __restrict__ Dp,
                                                    const float* __restrict__ gate_f,
                                                    const float* __restrict__ Ib,
                                                    bf16* __restrict__ y_h,
                                                    bf16* __restrict__ y_l) {
  int b = blockIdx.x, c = blockIdx.y, i = threadIdx.x;
  float A[16];
  {
    const float4* ap = (const float4*)&A_log[i * 16];
    #pragma unroll
    for (int q = 0; q < 4; ++q) {
      float4 a = ap[q];
      A[q * 4 + 0] = -__expf(a.x); A[q * 4 + 1] = -__expf(a.y);
      A[q * 4 + 2] = -__expf(a.z); A[q * 4 + 3] = -__expf(a.w);
    }
  }
  float st[16];
  {
    size_t base = ((size_t)(b * NCH + c) << 12) + i * 16;
    #pragma unroll
    for (int q = 0; q < 4; ++q) {
      float4 s4 = *(const float4*)&Ib[base + q * 4];
      st[q * 4 + 0] = s4.x; st[q * 4 + 1] = s4.y; st[q * 4 + 2] = s4.z; st[q * 4 + 3] = s4.w;
    }
  }
  float Dv = Dp[i];
  int t0 = b * LSEQ + c * CHL;
  for (int l = 0; l < CHL; ++l) {
    size_t t = t0 + l;
    float dtv = dtb[t * 256 + i];
    __hip_bfloat162 hp = hs_p[t * 256 + i];
    float hsv = __bfloat162float(hp.x) + __bfloat162float(hp.y);
    float dh = dtv * hsv;
    float Bv[16], Cv[16];
    #pragma unroll
    for (int q = 0; q < 4; ++q) {
      float4 bv = *(const float4*)&xp[t * 64 + 8 + q * 4];
      Bv[q * 4 + 0] = bv.x; Bv[q * 4 + 1] = bv.y; Bv[q * 4 + 2] = bv.z; Bv[q * 4 + 3] = bv.w;
      float4 cv = *(const float4*)&xp[t * 64 + 24 + q * 4];
      Cv[q * 4 + 0] = cv.x; Cv[q * 4 + 1] = cv.y; Cv[q * 4 + 2] = cv.z; Cv[q * 4 + 3] = cv.w;
    }
    float y0 = 0.f, y1 = 0.f, y2 = 0.f, y3 = 0.f;
    #pragma unroll
    for (int q = 0; q < 4; ++q) {
      float e0 = __expf(dtv * A[q * 4 + 0]);
      float e1 = __expf(dtv * A[q * 4 + 1]);
      float e2 = __expf(dtv * A[q * 4 + 2]);
      float e3 = __expf(dtv * A[q * 4 + 3]);
      st[q * 4 + 0] = fmaf(st[q * 4 + 0], e0, dh * Bv[q * 4 + 0]);
      st[q * 4 + 1] = fmaf(st[q * 4 + 1], e1, dh * Bv[q * 4 + 1]);
      st[q * 4 + 2] = fmaf(st[q * 4 + 2], e2, dh * Bv[q * 4 + 2]);
      st[q * 4 + 3] = fmaf(st[q * 4 + 3], e3, dh * Bv[q * 4 + 3]);
      y0 = fmaf(st[q * 4 + 0], Cv[q * 4 + 0], y0);
      y1 = fmaf(st[q * 4 + 1], Cv[q * 4 + 1], y1);
      y2 = fmaf(st[q * 4 + 2], Cv[q * 4 + 2], y2);
      y3 = fmaf(st[q * 4 + 3], Cv[q * 4 + 3], y3);
    }
    float y = ((y0 + y1) + (y2 + y3)) + hsv * Dv;
    float g = gate_f[t * 256 + i];
    float val = y * g;
    bf16 hh, ll;
    split_bf16(val, hh, ll);
    y_h[t * 256 + i] = hh;
    y_l[t * 256 + i] = ll;
  }
}

extern "C" void kernel_launch(void* const* d_in, const int* in_sizes, int n_in,
                              void* d_out, int out_size, void* d_ws, size_t ws_size,
                              hipStream_t stream) {
  const int* x           = (const int*)d_in[0];
  const float* embed     = (const float*)d_in[1];
  const float* in_proj_w = (const float*)d_in[2];
  const float* conv_w    = (const float*)d_in[3];
  const float* conv_b    = (const float*)d_in[4];
  const float* x_proj_w  = (const float*)d_in[5];
  const float* dt_proj_w = (const float*)d_in[6];
  const float* dt_proj_b = (const float*)d_in[7];
  const float* A_log     = (const float*)d_in[8];
  const float* Dp        = (const float*)d_in[9];
  const float* out_proj_w= (const float*)d_in[10];
  const float* norm_w    = (const float*)d_in[11];
  const float* norm_f_w  = (const float*)d_in[12];
  const float* head_w    = (const float*)d_in[13];
  const float* head_b    = (const float*)d_in[14];

  float* out = (float*)d_out;
  float* ws  = (float*)d_ws;

  // ---- d_out scratch map (f32 word offsets; budget 33,554,432) ----
  // Pb/Sb alias the y region: y dead from outproj until scanC rewrites it;
  // scanB fully consumes Pb/Sb before scanC writes y.
  float* hzx     = out;                          //  4,194,304 (T*256 f32)
  float* gate_f  = out + 4194304;                //  4,194,304 (T*256 f32)
  __hip_bfloat162* hs_p = (__hip_bfloat162*)(out + 8388608);   // 4,194,304 w (T*256 bf162)
  float* dtb     = out + 12582912;               //  4,194,304 (T*256 f32)
  float* xp      = out + 16777216;               //  1,048,576 (T*64 f32)
  float* Pb      = out + 17825792;               //  2,097,152 (512*4096) [aliases y_h]
  float* Sb      = out + 19922944;               //  2,097,152            [aliases y_l]
  bf16*  y_h     = (bf16*)(out + 17825792);      //  2,097,152 w
  bf16*  y_l     = (bf16*)(out + 19922944);      //  2,097,152 w
  float* h       = out + 22020096;               //  2,097,152 (T*128 residual)
  bf16*  w_in_h  = (bf16*)(out + 24117248);      //  1,048,576 w
  bf16*  w_in_l  = (bf16*)(out + 25165824);      //  1,048,576 w
  bf16*  w_x_h   = (bf16*)(out + 26214400);      //    262,144 w (padded 64 rows)
  bf16*  w_x_l   = (bf16*)(out + 26476544);
  bf16*  w_out_h = (bf16*)(out + 26738688);      //    524,288 w
  bf16*  w_out_l = (bf16*)(out + 27262976);
  float* Ib      = out + 27787264;               //  2,097,152 -> ends 29,884,416

  // ---- ws scratch (~9.4 MB) — live through the head GEMM ----
  bf16* hn_h     = (bf16*)ws;                    // T*128 bf16
  bf16* hn_l     = (bf16*)(ws + 1048576);
  bf16* w_head_h = (bf16*)(ws + 2097152);        // 2048*128 bf16
  bf16* w_head_l = (bf16*)(ws + 2228224);

  cast_split_kernel<<<8192, 256, 0, stream>>>(in_proj_w, w_in_h, w_in_l, 2097152);
  cast_xproj_kernel<<<2048, 256, 0, stream>>>(x_proj_w, w_x_h, w_x_l);
  cast_split_kernel<<<4096, 256, 0, stream>>>(out_proj_w, w_out_h, w_out_l, 1048576);
  cast_split_kernel<<<1024, 256, 0, stream>>>(head_w, w_head_h, w_head_l, 262144);

  embed_kernel<<<8192, 256, 0, stream>>>(x, embed, h);
  rmsnorm_split_kernel<<<4096, 256, 0, stream>>>(h, norm_w, hn_h, hn_l);

  for (int l = 0; l < 32; ++l) {
    inproj_kernel<<<dim3(128, 4), 256, 0, stream>>>(
        hn_h, hn_l, w_in_h + (size_t)l * 512 * 128, w_in_l + (size_t)l * 512 * 128,
        hzx, gate_f);
    xproj_scan_kernel<<<512, 256, 0, stream>>>(
        hzx, conv_w + l * 1024, conv_b + l * 256,
        w_x_h + (size_t)l * 64 * 256, w_x_l + (size_t)l * 64 * 256,
        dt_proj_w + l * 2048, dt_proj_b + l * 256, A_log + l * 4096,
        hs_p, xp, dtb, Pb, Sb);
    scanB_kernel<<<128, 256, 0, stream>>>(Pb, Sb, Ib);
    scanC_kernel<<<dim3(8, NCH), 256, 0, stream>>>(
        dtb, hs_p, xp, A_log + l * 4096, Dp + l * 256, gate_f, Ib, y_h, y_l);
    const float* nwnext = (l < 31) ? (norm_w + (l + 1) * 128) : norm_f_w;
    outproj_norm_kernel<<<512, 256, 0, stream>>>(
        y_h, y_l, w_out_h + (size_t)l * 128 * 256, w_out_l + (size_t)l * 128 * 256,
        nwnext, h, hn_h, hn_l);
  }

  mfma_gemm<128, 128, 2, 2, 2><<<dim3(128, 16), 256, 0, stream>>>(
      hn_h, hn_l, w_head_h, w_head_l, out, head_b, 2048, 128);
}

// Round 16
// 3132.439 us; speedup vs baseline: 4.1960x; 1.0585x over previous
//
#include <hip/hip_runtime.h>
#include <hip/hip_bf16.h>

#define LSEQ 2048
#define NCH 64          // chunks per sequence
#define CHL 32          // chunk length (NCH*CHL == LSEQ)

typedef __attribute__((ext_vector_type(8))) short bf16x8;
typedef __attribute__((ext_vector_type(4))) float f32x4;
typedef __hip_bfloat16 bf16;

__device__ __forceinline__ void gload_lds16(const void* g, void* l) {
  __builtin_amdgcn_global_load_lds(
      (const __attribute__((address_space(1))) void*)g,
      (__attribute__((address_space(3))) void*)l, 16, 0, 0);
}

__device__ __forceinline__ void split_bf16(float v, bf16& h, bf16& l) {
  h = __float2bfloat16(v);
  l = __float2bfloat16(v - __bfloat162float(h));
}

// ---------------- embed ----------------
__global__ __launch_bounds__(256) void embed_kernel(const int* __restrict__ x,
                                                    const float* __restrict__ emb,
                                                    float* __restrict__ h) {
  int idx = blockIdx.x * 256 + threadIdx.x;   // T*128
  int t = idx >> 7;
  int d = idx & 127;
  h[idx] = emb[(size_t)x[t] * 128 + d];
}

// ---------------- weight casts (hi/lo split) ----------------
__global__ __launch_bounds__(256) void cast_split_kernel(const float* __restrict__ src,
                                                         bf16* __restrict__ hi,
                                                         bf16* __restrict__ lo, int n) {
  int i = blockIdx.x * 256 + threadIdx.x;
  if (i < n) { bf16 h, l; split_bf16(src[i], h, l); hi[i] = h; lo[i] = l; }
}

// x_proj: src [32][40][256] -> dst [32][64][256], rows 40..63 zero
__global__ __launch_bounds__(256) void cast_xproj_kernel(const float* __restrict__ src,
                                                         bf16* __restrict__ hi,
                                                         bf16* __restrict__ lo) {
  int i = blockIdx.x * 256 + threadIdx.x;   // 32*64*256
  int k = i & 255, n = (i >> 8) & 63, l = i >> 14;
  float v = (n < 40) ? src[((size_t)l * 40 + n) * 256 + k] : 0.f;
  bf16 h, lw; split_bf16(v, h, lw);
  hi[i] = h; lo[i] = lw;
}

// ---------------- rmsnorm -> bf16 hi/lo (layer-0 input only) ----------------
__global__ __launch_bounds__(256) void rmsnorm_split_kernel(const float* __restrict__ hin,
                                                            const float* __restrict__ w,
                                                            bf16* __restrict__ hout_h,
                                                            bf16* __restrict__ hout_l) {
  int row = blockIdx.x * 4 + (threadIdx.x >> 6);
  int lane = threadIdx.x & 63;
  float2 v = *(const float2*)&hin[(size_t)row * 128 + lane * 2];
  float ss = v.x * v.x + v.y * v.y;
  #pragma unroll
  for (int m = 1; m < 64; m <<= 1) ss += __shfl_xor(ss, m);
  float rstd = rsqrtf(ss * (1.0f / 128.0f) + 1e-5f);
  float2 wv = *(const float2*)&w[lane * 2];
  float o0 = v.x * rstd * wv.x, o1 = v.y * rstd * wv.y;
  __hip_bfloat162 ph, pl;
  bf16 hh, ll;
  split_bf16(o0, hh, ll); ph.x = hh; pl.x = ll;
  split_bf16(o1, hh, ll); ph.y = hh; pl.y = ll;
  *(__hip_bfloat162*)&hout_h[(size_t)row * 128 + lane * 2] = ph;
  *(__hip_bfloat162*)&hout_l[(size_t)row * 128 + lane * 2] = pl;
}

// ================= generic split-bf16 MFMA GEMM (head) =================
template <int BM, int BN, int WR, int WC, int EPI>
__global__ __launch_bounds__(256) void mfma_gemm(const bf16* __restrict__ AH,
                                                 const bf16* __restrict__ AL,
                                                 const bf16* __restrict__ WH,
                                                 const bf16* __restrict__ WL,
                                                 float* __restrict__ C,
                                                 const float* __restrict__ bias,
                                                 int Nc, int Kc) {
  constexpr int WTM = BM / WR, WTN = BN / WC;
  constexpr int U = WTM / 16, V = WTN / 16;
  __shared__ bf16 AsH[BM * 64];
  __shared__ bf16 AsL[BM * 64];
  __shared__ bf16 BsH[BN * 64];
  __shared__ bf16 BsL[BN * 64];
  int tid = threadIdx.x;
  int lane = tid & 63, wid = tid >> 6;
  int wr = wid / WC, wc = wid % WC;
  int row0 = blockIdx.x * BM, col0 = blockIdx.y * BN;
  int l15 = lane & 15, l4 = lane >> 4;
  f32x4 acc[U][V] = {};
  for (int k0 = 0; k0 < Kc; k0 += 64) {
    __syncthreads();
    #pragma unroll
    for (int it = 0; it < BM / 32; ++it) {
      int chunk = it * 256 + tid;
      int r = chunk >> 3;
      int clog = (chunk & 7) ^ (r & 7);
      size_t goff = (size_t)(row0 + r) * Kc + k0 + clog * 8;
      gload_lds16(AH + goff, &AsH[chunk * 8]);
      gload_lds16(AL + goff, &AsL[chunk * 8]);
    }
    #pragma unroll
    for (int it = 0; it < BN / 32; ++it) {
      int chunk = it * 256 + tid;
      int r = chunk >> 3;
      int clog = (chunk & 7) ^ (r & 7);
      size_t goff = (size_t)(col0 + r) * Kc + k0 + clog * 8;
      gload_lds16(WH + goff, &BsH[chunk * 8]);
      gload_lds16(WL + goff, &BsL[chunk * 8]);
    }
    __syncthreads();
    #pragma unroll
    for (int kk = 0; kk < 2; ++kk) {
      bf16x8 afh[U], afl[U], bfh[V], bfl[V];
      #pragma unroll
      for (int u = 0; u < U; ++u) {
        int r = wr * WTM + u * 16 + l15;
        int csw = (kk * 4 + l4) ^ (r & 7);
        afh[u] = *(const bf16x8*)&AsH[r * 64 + csw * 8];
        afl[u] = *(const bf16x8*)&AsL[r * 64 + csw * 8];
      }
      #pragma unroll
      for (int v = 0; v < V; ++v) {
        int r = wc * WTN + v * 16 + l15;
        int csw = (kk * 4 + l4) ^ (r & 7);
        bfh[v] = *(const bf16x8*)&BsH[r * 64 + csw * 8];
        bfl[v] = *(const bf16x8*)&BsL[r * 64 + csw * 8];
      }
      #pragma unroll
      for (int u = 0; u < U; ++u)
        #pragma unroll
        for (int v = 0; v < V; ++v) {
          acc[u][v] = __builtin_amdgcn_mfma_f32_16x16x32_bf16(afh[u], bfh[v], acc[u][v], 0, 0, 0);
          acc[u][v] = __builtin_amdgcn_mfma_f32_16x16x32_bf16(afl[u], bfh[v], acc[u][v], 0, 0, 0);
          acc[u][v] = __builtin_amdgcn_mfma_f32_16x16x32_bf16(afh[u], bfl[v], acc[u][v], 0, 0, 0);
        }
    }
  }
  #pragma unroll
  for (int u = 0; u < U; ++u) {
    int rbase = row0 + wr * WTM + u * 16 + l4 * 4;
    #pragma unroll
    for (int v = 0; v < V; ++v) {
      int col = col0 + wc * WTN + v * 16 + l15;
      #pragma unroll
      for (int q = 0; q < 4; ++q) {
        size_t off = (size_t)(rbase + q) * Nc + col;
        float val = acc[u][v][q];
        if (EPI == 2) val += bias[col];
        C[off] = val;
      }
    }
  }
}

// ================= in_proj (128x128, K=128): writes hzx(f32) / silu(gate)(f32) =================
__global__ __launch_bounds__(256) void inproj_kernel(const bf16* __restrict__ AH,
                                                     const bf16* __restrict__ AL,
                                                     const bf16* __restrict__ WH,
                                                     const bf16* __restrict__ WL,
                                                     float* __restrict__ hzx,
                                                     float* __restrict__ gate_f) {
  constexpr int BM = 128, BN = 128;
  __shared__ bf16 AsH[BM * 64];
  __shared__ bf16 AsL[BM * 64];
  __shared__ bf16 BsH[BN * 64];
  __shared__ bf16 BsL[BN * 64];
  int tid = threadIdx.x;
  int lane = tid & 63, wid = tid >> 6;
  int wr = wid >> 1, wc = wid & 1;
  int row0 = blockIdx.x * BM, col0 = blockIdx.y * BN;
  int l15 = lane & 15, l4 = lane >> 4;
  f32x4 acc[4][4] = {};
  for (int k0 = 0; k0 < 128; k0 += 64) {
    __syncthreads();
    #pragma unroll
    for (int it = 0; it < 4; ++it) {
      int chunk = it * 256 + tid;
      int r = chunk >> 3;
      int clog = (chunk & 7) ^ (r & 7);
      size_t goff = (size_t)(row0 + r) * 128 + k0 + clog * 8;
      gload_lds16(AH + goff, &AsH[chunk * 8]);
      gload_lds16(AL + goff, &AsL[chunk * 8]);
      size_t woff = (size_t)(col0 + r) * 128 + k0 + clog * 8;
      gload_lds16(WH + woff, &BsH[chunk * 8]);
      gload_lds16(WL + woff, &BsL[chunk * 8]);
    }
    __syncthreads();
    #pragma unroll
    for (int kk = 0; kk < 2; ++kk) {
      bf16x8 afh[4], afl[4], bfh[4], bfl[4];
      #pragma unroll
      for (int u = 0; u < 4; ++u) {
        int r = wr * 64 + u * 16 + l15;
        int csw = (kk * 4 + l4) ^ (r & 7);
        afh[u] = *(const bf16x8*)&AsH[r * 64 + csw * 8];
        afl[u] = *(const bf16x8*)&AsL[r * 64 + csw * 8];
      }
      #pragma unroll
      for (int v = 0; v < 4; ++v) {
        int r = wc * 64 + v * 16 + l15;
        int csw = (kk * 4 + l4) ^ (r & 7);
        bfh[v] = *(const bf16x8*)&BsH[r * 64 + csw * 8];
        bfl[v] = *(const bf16x8*)&BsL[r * 64 + csw * 8];
      }
      #pragma unroll
      for (int u = 0; u < 4; ++u)
        #pragma unroll
        for (int v = 0; v < 4; ++v) {
          acc[u][v] = __builtin_amdgcn_mfma_f32_16x16x32_bf16(afh[u], bfh[v], acc[u][v], 0, 0, 0);
          acc[u][v] = __builtin_amdgcn_mfma_f32_16x16x32_bf16(afl[u], bfh[v], acc[u][v], 0, 0, 0);
          acc[u][v] = __builtin_amdgcn_mfma_f32_16x16x32_bf16(afh[u], bfl[v], acc[u][v], 0, 0, 0);
        }
    }
  }
  bool isgate = (col0 >= 256);
  #pragma unroll
  for (int u = 0; u < 4; ++u) {
    int rbase = row0 + wr * 64 + u * 16 + l4 * 4;
    #pragma unroll
    for (int v = 0; v < 4; ++v) {
      int col = col0 + wc * 64 + v * 16 + l15;
      #pragma unroll
      for (int q = 0; q < 4; ++q) {
        float val = acc[u][v][q];
        if (!isgate) {
          hzx[(size_t)(rbase + q) * 256 + col] = val;
        } else {
          float s = val / (1.0f + __expf(-val));
          gate_f[(size_t)(rbase + q) * 256 + (col - 256)] = s;
        }
      }
    }
  }
}

// ================= x_proj (32x64, K=256) + conv/silu staging + dt + FUSED chunk-scan (phase A) ======
// Block bid covers tokens [bid*32, bid*32+32) == scan chunk (b = bid>>6, c = bid&63).
__global__ __launch_bounds__(256) void xproj_scan_kernel(const float* __restrict__ hzx,
                                                         const float* __restrict__ cw,
                                                         const float* __restrict__ cb,
                                                         const bf16* __restrict__ WH,
                                                         const bf16* __restrict__ WL,
                                                         const float* __restrict__ Wdt,
                                                         const float* __restrict__ bdt,
                                                         const float* __restrict__ A_log,
                                                         __hip_bfloat162* __restrict__ hs_p,
                                                         float* __restrict__ xp,
                                                         float* __restrict__ dtb,
                                                         float* __restrict__ Pb,
                                                         float* __restrict__ Sb) {
  __shared__ bf16 AsH[32 * 64];
  __shared__ bf16 AsL[32 * 64];
  __shared__ bf16 BsH[64 * 64];
  __shared__ bf16 BsL[64 * 64];
  __shared__ float xq[32][24];                 // xp cols 0..23 (dt inputs + B)
  __shared__ __hip_bfloat162 hs_lds[32][257];  // +1 pad: conflict-free
  int tid = threadIdx.x;
  int lane = tid & 63, wid = tid >> 6;
  int wr = wid >> 1, wc = wid & 1;   // wave tile 16x32
  int row0 = blockIdx.x * 32;
  int l15 = lane & 15, l4 = lane >> 4;
  int r = tid >> 3, cslot = tid & 7;
  int tok = row0 + r;
  int lpos = tok & (LSEQ - 1);   // 32 | LSEQ, blocks never straddle sequences
  f32x4 acc[1][2] = {};
  for (int k0 = 0; k0 < 256; k0 += 64) {
    __syncthreads();
    {
      int kb = k0 + ((cslot ^ (r & 7)) << 3);
      const float* hp = &hzx[(size_t)tok * 256 + kb];
      float x3[8], x2[8], x1[8], x0[8];
      *(float4*)&x3[0] = *(const float4*)(hp);
      *(float4*)&x3[4] = *(const float4*)(hp + 4);
      if (lpos >= 1) { *(float4*)&x2[0] = *(const float4*)(hp - 256); *(float4*)&x2[4] = *(const float4*)(hp - 252); }
      else { *(float4*)&x2[0] = make_float4(0,0,0,0); *(float4*)&x2[4] = make_float4(0,0,0,0); }
      if (lpos >= 2) { *(float4*)&x1[0] = *(const float4*)(hp - 512); *(float4*)&x1[4] = *(const float4*)(hp - 508); }
      else { *(float4*)&x1[0] = make_float4(0,0,0,0); *(float4*)&x1[4] = make_float4(0,0,0,0); }
      if (lpos >= 3) { *(float4*)&x0[0] = *(const float4*)(hp - 768); *(float4*)&x0[4] = *(const float4*)(hp - 764); }
      else { *(float4*)&x0[0] = make_float4(0,0,0,0); *(float4*)&x0[4] = make_float4(0,0,0,0); }
      bf16 tH[8], tL[8];
      __hip_bfloat162 pk[8];
      #pragma unroll
      for (int j = 0; j < 8; ++j) {
        float4 w = *(const float4*)&cw[(kb + j) * 4];
        float s = cb[kb + j];
        s = fmaf(x0[j], w.x, s);
        s = fmaf(x1[j], w.y, s);
        s = fmaf(x2[j], w.z, s);
        s = fmaf(x3[j], w.w, s);
        s = s / (1.0f + __expf(-s));
        split_bf16(s, tH[j], tL[j]);
        pk[j].x = tH[j]; pk[j].y = tL[j];
        hs_lds[r][kb + j] = pk[j];
      }
      *(bf16x8*)&AsH[tid * 8] = *(const bf16x8*)tH;
      *(bf16x8*)&AsL[tid * 8] = *(const bf16x8*)tL;
      *(float4*)&hs_p[(size_t)tok * 256 + kb]     = *(const float4*)&pk[0];
      *(float4*)&hs_p[(size_t)tok * 256 + kb + 4] = *(const float4*)&pk[4];
    }
    #pragma unroll
    for (int it = 0; it < 2; ++it) {
      int chunk = it * 256 + tid;
      int rr = chunk >> 3;
      int clog = (chunk & 7) ^ (rr & 7);
      size_t goff = (size_t)rr * 256 + k0 + clog * 8;
      gload_lds16(WH + goff, &BsH[chunk * 8]);
      gload_lds16(WL + goff, &BsL[chunk * 8]);
    }
    __syncthreads();
    #pragma unroll
    for (int kk = 0; kk < 2; ++kk) {
      bf16x8 afh, afl, bfh[2], bfl[2];
      {
        int rr = wr * 16 + l15;
        int csw = (kk * 4 + l4) ^ (rr & 7);
        afh = *(const bf16x8*)&AsH[rr * 64 + csw * 8];
        afl = *(const bf16x8*)&AsL[rr * 64 + csw * 8];
      }
      #pragma unroll
      for (int v = 0; v < 2; ++v) {
        int rr = wc * 32 + v * 16 + l15;
        int csw = (kk * 4 + l4) ^ (rr & 7);
        bfh[v] = *(const bf16x8*)&BsH[rr * 64 + csw * 8];
        bfl[v] = *(const bf16x8*)&BsL[rr * 64 + csw * 8];
      }
      #pragma unroll
      for (int v = 0; v < 2; ++v) {
        acc[0][v] = __builtin_amdgcn_mfma_f32_16x16x32_bf16(afh, bfh[v], acc[0][v], 0, 0, 0);
        acc[0][v] = __builtin_amdgcn_mfma_f32_16x16x32_bf16(afl, bfh[v], acc[0][v], 0, 0, 0);
        acc[0][v] = __builtin_amdgcn_mfma_f32_16x16x32_bf16(afh, bfl[v], acc[0][v], 0, 0, 0);
      }
    }
  }
  // epilogue: write xp; stash cols 0..23 into LDS
  {
    int rbase = wr * 16 + l4 * 4;
    #pragma unroll
    for (int v = 0; v < 2; ++v) {
      int col = wc * 32 + v * 16 + l15;
      #pragma unroll
      for (int q = 0; q < 4; ++q) {
        float val = acc[0][v][q];
        xp[(size_t)(row0 + rbase + q) * 64 + col] = val;
        if (col < 24) xq[rbase + q][col] = val;
      }
    }
  }
  __syncthreads();
  // dt + chunk-scan phase: thread i owns channel i, 16 states in registers
  {
    int i = tid;
    float A[16];
    {
      const float4* ap = (const float4*)&A_log[i * 16];
      #pragma unroll
      for (int q = 0; q < 4; ++q) {
        float4 a = ap[q];
        A[q * 4 + 0] = -__expf(a.x); A[q * 4 + 1] = -__expf(a.y);
        A[q * 4 + 2] = -__expf(a.z); A[q * 4 + 3] = -__expf(a.w);
      }
    }
    const float* wr8 = Wdt + i * 8;
    float w0 = wr8[0], w1 = wr8[1], w2 = wr8[2], w3 = wr8[3];
    float w4 = wr8[4], w5 = wr8[5], w6 = wr8[6], w7 = wr8[7];
    float bv = bdt[i];
    float P[16], S[16];
    #pragma unroll
    for (int n = 0; n < 16; ++n) { P[n] = 1.0f; S[n] = 0.0f; }
    for (int tt = 0; tt < 32; ++tt) {
      const float* q = xq[tt];
      float s = bv;
      s = fmaf(q[0], w0, s); s = fmaf(q[1], w1, s);
      s = fmaf(q[2], w2, s); s = fmaf(q[3], w3, s);
      s = fmaf(q[4], w4, s); s = fmaf(q[5], w5, s);
      s = fmaf(q[6], w6, s); s = fmaf(q[7], w7, s);
      float dtv = (s > 20.0f) ? s : log1pf(__expf(s));
      dtb[(size_t)(row0 + tt) * 256 + i] = dtv;
      __hip_bfloat162 hp = hs_lds[tt][i];
      float hsv = __bfloat162float(hp.x) + __bfloat162float(hp.y);
      float dh = dtv * hsv;
      #pragma unroll
      for (int n = 0; n < 16; ++n) {
        float e = __expf(dtv * A[n]);
        P[n] *= e;
        S[n] = fmaf(S[n], e, dh * q[8 + n]);
      }
    }
    size_t base = ((size_t)blockIdx.x << 12) + i * 16;
    #pragma unroll
    for (int qq = 0; qq < 4; ++qq) {
      *(float4*)&Pb[base + qq * 4] = make_float4(P[qq * 4], P[qq * 4 + 1], P[qq * 4 + 2], P[qq * 4 + 3]);
      *(float4*)&Sb[base + qq * 4] = make_float4(S[qq * 4], S[qq * 4 + 1], S[qq * 4 + 2], S[qq * 4 + 3]);
    }
  }
}

// phase B: sequential prefix over chunks -> initial states. 32768 threads.
__global__ __launch_bounds__(256) void scanB_kernel(const float* __restrict__ Pb,
                                                    const float* __restrict__ Sb,
                                                    float* __restrict__ Ib) {
  int g = blockIdx.x * 256 + threadIdx.x;   // b*4096 + i*16 + n
  int b = g >> 12, rem = g & 4095;
  float s = 0.0f;
  for (int cc = 0; cc < NCH; ++cc) {
    size_t off = ((size_t)(b * NCH + cc) << 12) + rem;
    Ib[off] = s;
    s = fmaf(s, Pb[off], Sb[off]);
  }
}

// ================= out_proj (32x128, K=256) + FUSED scan phase C + residual + next-layer RMSNorm ====
// Block bid covers tokens [bid*32, bid*32+32) == scan chunk; y computed in-kernel into LDS.
__global__ __launch_bounds__(256) void outproj_scan_norm_kernel(const float* __restrict__ dtb,
                                                                const __hip_bfloat162* __restrict__ hs_p,
                                                                const float* __restrict__ xp,
                                                                const float* __restrict__ A_log,
                                                                const float* __restrict__ Dp,
                                                                const float* __restrict__ gate_f,
                                                                const float* __restrict__ Ib,
                                                                const bf16* __restrict__ WH,
                                                                const bf16* __restrict__ WL,
                                                                const float* __restrict__ nw,
                                                                float* __restrict__ Ch,
                                                                bf16* __restrict__ hn_h,
                                                                bf16* __restrict__ hn_l) {
  __shared__ bf16 AsH[32 * 64];
  __shared__ bf16 AsL[32 * 64];
  __shared__ bf16 BsH[128 * 64];
  __shared__ bf16 BsL[128 * 64];
  __shared__ __hip_bfloat162 y_lds[32][257];   // +1 pad
  __shared__ float ssq[32][2];
  int tid = threadIdx.x;
  int lane = tid & 63, wid = tid >> 6;
  int wr = wid >> 1, wc = wid & 1;    // wave tile 16x64
  int row0 = blockIdx.x * 32;
  int l15 = lane & 15, l4 = lane >> 4;
  // ---- phase C: thread i = channel i, replay chunk with initial state from Ib ----
  {
    int i = tid;
    float A[16];
    {
      const float4* ap = (const float4*)&A_log[i * 16];
      #pragma unroll
      for (int q = 0; q < 4; ++q) {
        float4 a = ap[q];
        A[q * 4 + 0] = -__expf(a.x); A[q * 4 + 1] = -__expf(a.y);
        A[q * 4 + 2] = -__expf(a.z); A[q * 4 + 3] = -__expf(a.w);
      }
    }
    float st[16];
    {
      size_t base = ((size_t)blockIdx.x << 12) + i * 16;
      #pragma unroll
      for (int q = 0; q < 4; ++q) {
        float4 s4 = *(const float4*)&Ib[base + q * 4];
        st[q * 4 + 0] = s4.x; st[q * 4 + 1] = s4.y; st[q * 4 + 2] = s4.z; st[q * 4 + 3] = s4.w;
      }
    }
    float Dv = Dp[i];
    for (int tt = 0; tt < 32; ++tt) {
      size_t t = row0 + tt;
      float dtv = dtb[t * 256 + i];
      __hip_bfloat162 hp = hs_p[t * 256 + i];
      float hsv = __bfloat162float(hp.x) + __bfloat162float(hp.y);
      float dh = dtv * hsv;
      float Bv[16], Cv[16];
      #pragma unroll
      for (int q = 0; q < 4; ++q) {
        float4 bv = *(const float4*)&xp[t * 64 + 8 + q * 4];
        Bv[q * 4 + 0] = bv.x; Bv[q * 4 + 1] = bv.y; Bv[q * 4 + 2] = bv.z; Bv[q * 4 + 3] = bv.w;
        float4 cv = *(const float4*)&xp[t * 64 + 24 + q * 4];
        Cv[q * 4 + 0] = cv.x; Cv[q * 4 + 1] = cv.y; Cv[q * 4 + 2] = cv.z; Cv[q * 4 + 3] = cv.w;
      }
      float y0 = 0.f, y1 = 0.f, y2 = 0.f, y3 = 0.f;
      #pragma unroll
      for (int q = 0; q < 4; ++q) {
        float e0 = __expf(dtv * A[q * 4 + 0]);
        float e1 = __expf(dtv * A[q * 4 + 1]);
        float e2 = __expf(dtv * A[q * 4 + 2]);
        float e3 = __expf(dtv * A[q * 4 + 3]);
        st[q * 4 + 0] = fmaf(st[q * 4 + 0], e0, dh * Bv[q * 4 + 0]);
        st[q * 4 + 1] = fmaf(st[q * 4 + 1], e1, dh * Bv[q * 4 + 1]);
        st[q * 4 + 2] = fmaf(st[q * 4 + 2], e2, dh * Bv[q * 4 + 2]);
        st[q * 4 + 3] = fmaf(st[q * 4 + 3], e3, dh * Bv[q * 4 + 3]);
        y0 = fmaf(st[q * 4 + 0], Cv[q * 4 + 0], y0);
        y1 = fmaf(st[q * 4 + 1], Cv[q * 4 + 1], y1);
        y2 = fmaf(st[q * 4 + 2], Cv[q * 4 + 2], y2);
        y3 = fmaf(st[q * 4 + 3], Cv[q * 4 + 3], y3);
      }
      float y = ((y0 + y1) + (y2 + y3)) + hsv * Dv;
      float g = gate_f[t * 256 + i];
      float val = y * g;
      bf16 hh, ll;
      split_bf16(val, hh, ll);
      __hip_bfloat162 pk; pk.x = hh; pk.y = ll;
      y_lds[tt][i] = pk;
    }
  }
  // ---- GEMM: A from y_lds, B from global ----
  f32x4 acc[1][4] = {};
  for (int k0 = 0; k0 < 256; k0 += 64) {
    __syncthreads();
    {
      int chunk = tid;
      int r = chunk >> 3;
      int kb = k0 + (((chunk & 7) ^ (r & 7)) << 3);
      bf16 tH[8], tL[8];
      #pragma unroll
      for (int j = 0; j < 8; ++j) {
        __hip_bfloat162 pk = y_lds[r][kb + j];
        tH[j] = pk.x; tL[j] = pk.y;
      }
      *(bf16x8*)&AsH[tid * 8] = *(const bf16x8*)tH;
      *(bf16x8*)&AsL[tid * 8] = *(const bf16x8*)tL;
    }
    #pragma unroll
    for (int it = 0; it < 4; ++it) {
      int chunk = it * 256 + tid;
      int r = chunk >> 3;
      int clog = (chunk & 7) ^ (r & 7);
      size_t goff = (size_t)r * 256 + k0 + clog * 8;
      gload_lds16(WH + goff, &BsH[chunk * 8]);
      gload_lds16(WL + goff, &BsL[chunk * 8]);
    }
    __syncthreads();
    #pragma unroll
    for (int kk = 0; kk < 2; ++kk) {
      bf16x8 afh, afl, bfh[4], bfl[4];
      {
        int r = wr * 16 + l15;
        int csw = (kk * 4 + l4) ^ (r & 7);
        afh = *(const bf16x8*)&AsH[r * 64 + csw * 8];
        afl = *(const bf16x8*)&AsL[r * 64 + csw * 8];
      }
      #pragma unroll
      for (int v = 0; v < 4; ++v) {
        int r = wc * 64 + v * 16 + l15;
        int csw = (kk * 4 + l4) ^ (r & 7);
        bfh[v] = *(const bf16x8*)&BsH[r * 64 + csw * 8];
        bfl[v] = *(const bf16x8*)&BsL[r * 64 + csw * 8];
      }
      #pragma unroll
      for (int v = 0; v < 4; ++v) {
        acc[0][v] = __builtin_amdgcn_mfma_f32_16x16x32_bf16(afh, bfh[v], acc[0][v], 0, 0, 0);
        acc[0][v] = __builtin_amdgcn_mfma_f32_16x16x32_bf16(afl, bfh[v], acc[0][v], 0, 0, 0);
        acc[0][v] = __builtin_amdgcn_mfma_f32_16x16x32_bf16(afh, bfl[v], acc[0][v], 0, 0, 0);
      }
    }
  }
  int rloc = wr * 16 + l4 * 4;
  float vals[4][4];   // [q][v]
  #pragma unroll
  for (int v = 0; v < 4; ++v) {
    int col = wc * 64 + v * 16 + l15;
    #pragma unroll
    for (int q = 0; q < 4; ++q) {
      size_t off = (size_t)(row0 + rloc + q) * 128 + col;
      float val = acc[0][v][q] + Ch[off];
      vals[q][v] = val;
      Ch[off] = val;
    }
  }
  #pragma unroll
  for (int q = 0; q < 4; ++q) {
    float ss = vals[q][0] * vals[q][0] + vals[q][1] * vals[q][1]
             + vals[q][2] * vals[q][2] + vals[q][3] * vals[q][3];
    ss += __shfl_xor(ss, 1, 16);
    ss += __shfl_xor(ss, 2, 16);
    ss += __shfl_xor(ss, 4, 16);
    ss += __shfl_xor(ss, 8, 16);
    if (l15 == 0) ssq[rloc + q][wc] = ss;
  }
  __syncthreads();
  #pragma unroll
  for (int q = 0; q < 4; ++q) {
    float rstd = rsqrtf((ssq[rloc + q][0] + ssq[rloc + q][1]) * (1.0f / 128.0f) + 1e-5f);
    #pragma unroll
    for (int v = 0; v < 4; ++v) {
      int col = wc * 64 + v * 16 + l15;
      float o = vals[q][v] * rstd * nw[col];
      bf16 hh, ll;
      split_bf16(o, hh, ll);
      size_t off = (size_t)(row0 + rloc + q) * 128 + col;
      hn_h[off] = hh;
      hn_l[off] = ll;
    }
  }
}

extern "C" void kernel_launch(void* const* d_in, const int* in_sizes, int n_in,
                              void* d_out, int out_size, void* d_ws, size_t ws_size,
                              hipStream_t stream) {
  const int* x           = (const int*)d_in[0];
  const float* embed     = (const float*)d_in[1];
  const float* in_proj_w = (const float*)d_in[2];
  const float* conv_w    = (const float*)d_in[3];
  const float* conv_b    = (const float*)d_in[4];
  const float* x_proj_w  = (const float*)d_in[5];
  const float* dt_proj_w = (const float*)d_in[6];
  const float* dt_proj_b = (const float*)d_in[7];
  const float* A_log     = (const float*)d_in[8];
  const float* Dp        = (const float*)d_in[9];
  const float* out_proj_w= (const float*)d_in[10];
  const float* norm_w    = (const float*)d_in[11];
  const float* norm_f_w  = (const float*)d_in[12];
  const float* head_w    = (const float*)d_in[13];
  const float* head_b    = (const float*)d_in[14];

  float* out = (float*)d_out;
  float* ws  = (float*)d_ws;

  // ---- d_out scratch map (f32 word offsets; budget 33,554,432) ----
  float* hzx     = out;                          //  4,194,304 (T*256 f32)
  float* gate_f  = out + 4194304;                //  4,194,304 (T*256 f32)
  __hip_bfloat162* hs_p = (__hip_bfloat162*)(out + 8388608);   // 4,194,304 w (T*256 bf162)
  float* dtb     = out + 12582912;               //  4,194,304 (T*256 f32)
  float* xp      = out + 16777216;               //  1,048,576 (T*64 f32)
  float* Pb      = out + 17825792;               //  2,097,152 (512*4096)
  float* Sb      = out + 19922944;               //  2,097,152
  float* h       = out + 22020096;               //  2,097,152 (T*128 residual)
  bf16*  w_in_h  = (bf16*)(out + 24117248);      //  1,048,576 w
  bf16*  w_in_l  = (bf16*)(out + 25165824);      //  1,048,576 w
  bf16*  w_x_h   = (bf16*)(out + 26214400);      //    262,144 w (padded 64 rows)
  bf16*  w_x_l   = (bf16*)(out + 26476544);
  bf16*  w_out_h = (bf16*)(out + 26738688);      //    524,288 w
  bf16*  w_out_l = (bf16*)(out + 27262976);
  float* Ib      = out + 27787264;               //  2,097,152 -> ends 29,884,416

  // ---- ws scratch (~9.4 MB) — live through the head GEMM ----
  bf16* hn_h     = (bf16*)ws;                    // T*128 bf16
  bf16* hn_l     = (bf16*)(ws + 1048576);
  bf16* w_head_h = (bf16*)(ws + 2097152);        // 2048*128 bf16
  bf16* w_head_l = (bf16*)(ws + 2228224);

  cast_split_kernel<<<8192, 256, 0, stream>>>(in_proj_w, w_in_h, w_in_l, 2097152);
  cast_xproj_kernel<<<2048, 256, 0, stream>>>(x_proj_w, w_x_h, w_x_l);
  cast_split_kernel<<<4096, 256, 0, stream>>>(out_proj_w, w_out_h, w_out_l, 1048576);
  cast_split_kernel<<<1024, 256, 0, stream>>>(head_w, w_head_h, w_head_l, 262144);

  embed_kernel<<<8192, 256, 0, stream>>>(x, embed, h);
  rmsnorm_split_kernel<<<4096, 256, 0, stream>>>(h, norm_w, hn_h, hn_l);

  for (int l = 0; l < 32; ++l) {
    inproj_kernel<<<dim3(128, 4), 256, 0, stream>>>(
        hn_h, hn_l, w_in_h + (size_t)l * 512 * 128, w_in_l + (size_t)l * 512 * 128,
        hzx, gate_f);
    xproj_scan_kernel<<<512, 256, 0, stream>>>(
        hzx, conv_w + l * 1024, conv_b + l * 256,
        w_x_h + (size_t)l * 64 * 256, w_x_l + (size_t)l * 64 * 256,
        dt_proj_w + l * 2048, dt_proj_b + l * 256, A_log + l * 4096,
        hs_p, xp, dtb, Pb, Sb);
    scanB_kernel<<<128, 256, 0, stream>>>(Pb, Sb, Ib);
    const float* nwnext = (l < 31) ? (norm_w + (l + 1) * 128) : norm_f_w;
    outproj_scan_norm_kernel<<<512, 256, 0, stream>>>(
        dtb, hs_p, xp, A_log + l * 4096, Dp + l * 256, gate_f, Ib,
        w_out_h + (size_t)l * 128 * 256, w_out_l + (size_t)l * 128 * 256,
        nwnext, h, hn_h, hn_l);
  }

  mfma_gemm<128, 128, 2, 2, 2><<<dim3(128, 16), 256, 0, stream>>>(
      hn_h, hn_l, w_head_h, w_head_l, out, head_b, 2048, 128);
}

// Round 17
// 3129.482 us; speedup vs baseline: 4.2000x; 1.0009x over previous
//
#include <hip/hip_runtime.h>
#include <hip/hip_bf16.h>

#define LSEQ 2048
#define NCH 64          // chunks per sequence
#define CHL 32          // chunk length (NCH*CHL == LSEQ)

typedef __attribute__((ext_vector_type(8))) short bf16x8;
typedef __attribute__((ext_vector_type(4))) float f32x4;
typedef __hip_bfloat16 bf16;

__device__ __forceinline__ void gload_lds16(const void* g, void* l) {
  __builtin_amdgcn_global_load_lds(
      (const __attribute__((address_space(1))) void*)g,
      (__attribute__((address_space(3))) void*)l, 16, 0, 0);
}

__device__ __forceinline__ void split_bf16(float v, bf16& h, bf16& l) {
  h = __float2bfloat16(v);
  l = __float2bfloat16(v - __bfloat162float(h));
}

// ---------------- embed ----------------
__global__ __launch_bounds__(256) void embed_kernel(const int* __restrict__ x,
                                                    const float* __restrict__ emb,
                                                    float* __restrict__ h) {
  int idx = blockIdx.x * 256 + threadIdx.x;   // T*128
  int t = idx >> 7;
  int d = idx & 127;
  h[idx] = emb[(size_t)x[t] * 128 + d];
}

// ---------------- weight casts (hi/lo split) ----------------
__global__ __launch_bounds__(256) void cast_split_kernel(const float* __restrict__ src,
                                                         bf16* __restrict__ hi,
                                                         bf16* __restrict__ lo, int n) {
  int i = blockIdx.x * 256 + threadIdx.x;
  if (i < n) { bf16 h, l; split_bf16(src[i], h, l); hi[i] = h; lo[i] = l; }
}

// x_proj: src [32][40][256] -> dst [32][64][256], rows 40..63 zero
__global__ __launch_bounds__(256) void cast_xproj_kernel(const float* __restrict__ src,
                                                         bf16* __restrict__ hi,
                                                         bf16* __restrict__ lo) {
  int i = blockIdx.x * 256 + threadIdx.x;   // 32*64*256
  int k = i & 255, n = (i >> 8) & 63, l = i >> 14;
  float v = (n < 40) ? src[((size_t)l * 40 + n) * 256 + k] : 0.f;
  bf16 h, lw; split_bf16(v, h, lw);
  hi[i] = h; lo[i] = lw;
}

// ---------------- rmsnorm -> bf16 hi/lo (layer-0 input only) ----------------
__global__ __launch_bounds__(256) void rmsnorm_split_kernel(const float* __restrict__ hin,
                                                            const float* __restrict__ w,
                                                            bf16* __restrict__ hout_h,
                                                            bf16* __restrict__ hout_l) {
  int row = blockIdx.x * 4 + (threadIdx.x >> 6);
  int lane = threadIdx.x & 63;
  float2 v = *(const float2*)&hin[(size_t)row * 128 + lane * 2];
  float ss = v.x * v.x + v.y * v.y;
  #pragma unroll
  for (int m = 1; m < 64; m <<= 1) ss += __shfl_xor(ss, m);
  float rstd = rsqrtf(ss * (1.0f / 128.0f) + 1e-5f);
  float2 wv = *(const float2*)&w[lane * 2];
  float o0 = v.x * rstd * wv.x, o1 = v.y * rstd * wv.y;
  __hip_bfloat162 ph, pl;
  bf16 hh, ll;
  split_bf16(o0, hh, ll); ph.x = hh; pl.x = ll;
  split_bf16(o1, hh, ll); ph.y = hh; pl.y = ll;
  *(__hip_bfloat162*)&hout_h[(size_t)row * 128 + lane * 2] = ph;
  *(__hip_bfloat162*)&hout_l[(size_t)row * 128 + lane * 2] = pl;
}

// ================= generic split-bf16 MFMA GEMM (head) =================
template <int BM, int BN, int WR, int WC, int EPI>
__global__ __launch_bounds__(256) void mfma_gemm(const bf16* __restrict__ AH,
                                                 const bf16* __restrict__ AL,
                                                 const bf16* __restrict__ WH,
                                                 const bf16* __restrict__ WL,
                                                 float* __restrict__ C,
                                                 const float* __restrict__ bias,
                                                 int Nc, int Kc) {
  constexpr int WTM = BM / WR, WTN = BN / WC;
  constexpr int U = WTM / 16, V = WTN / 16;
  __shared__ bf16 AsH[BM * 64];
  __shared__ bf16 AsL[BM * 64];
  __shared__ bf16 BsH[BN * 64];
  __shared__ bf16 BsL[BN * 64];
  int tid = threadIdx.x;
  int lane = tid & 63, wid = tid >> 6;
  int wr = wid / WC, wc = wid % WC;
  int row0 = blockIdx.x * BM, col0 = blockIdx.y * BN;
  int l15 = lane & 15, l4 = lane >> 4;
  f32x4 acc[U][V] = {};
  for (int k0 = 0; k0 < Kc; k0 += 64) {
    __syncthreads();
    #pragma unroll
    for (int it = 0; it < BM / 32; ++it) {
      int chunk = it * 256 + tid;
      int r = chunk >> 3;
      int clog = (chunk & 7) ^ (r & 7);
      size_t goff = (size_t)(row0 + r) * Kc + k0 + clog * 8;
      gload_lds16(AH + goff, &AsH[chunk * 8]);
      gload_lds16(AL + goff, &AsL[chunk * 8]);
    }
    #pragma unroll
    for (int it = 0; it < BN / 32; ++it) {
      int chunk = it * 256 + tid;
      int r = chunk >> 3;
      int clog = (chunk & 7) ^ (r & 7);
      size_t goff = (size_t)(col0 + r) * Kc + k0 + clog * 8;
      gload_lds16(WH + goff, &BsH[chunk * 8]);
      gload_lds16(WL + goff, &BsL[chunk * 8]);
    }
    __syncthreads();
    #pragma unroll
    for (int kk = 0; kk < 2; ++kk) {
      bf16x8 afh[U], afl[U], bfh[V], bfl[V];
      #pragma unroll
      for (int u = 0; u < U; ++u) {
        int r = wr * WTM + u * 16 + l15;
        int csw = (kk * 4 + l4) ^ (r & 7);
        afh[u] = *(const bf16x8*)&AsH[r * 64 + csw * 8];
        afl[u] = *(const bf16x8*)&AsL[r * 64 + csw * 8];
      }
      #pragma unroll
      for (int v = 0; v < V; ++v) {
        int r = wc * WTN + v * 16 + l15;
        int csw = (kk * 4 + l4) ^ (r & 7);
        bfh[v] = *(const bf16x8*)&BsH[r * 64 + csw * 8];
        bfl[v] = *(const bf16x8*)&BsL[r * 64 + csw * 8];
      }
      #pragma unroll
      for (int u = 0; u < U; ++u)
        #pragma unroll
        for (int v = 0; v < V; ++v) {
          acc[u][v] = __builtin_amdgcn_mfma_f32_16x16x32_bf16(afh[u], bfh[v], acc[u][v], 0, 0, 0);
          acc[u][v] = __builtin_amdgcn_mfma_f32_16x16x32_bf16(afl[u], bfh[v], acc[u][v], 0, 0, 0);
          acc[u][v] = __builtin_amdgcn_mfma_f32_16x16x32_bf16(afh[u], bfl[v], acc[u][v], 0, 0, 0);
        }
    }
  }
  #pragma unroll
  for (int u = 0; u < U; ++u) {
    int rbase = row0 + wr * WTM + u * 16 + l4 * 4;
    #pragma unroll
    for (int v = 0; v < V; ++v) {
      int col = col0 + wc * WTN + v * 16 + l15;
      #pragma unroll
      for (int q = 0; q < 4; ++q) {
        size_t off = (size_t)(rbase + q) * Nc + col;
        float val = acc[u][v][q];
        if (EPI == 2) val += bias[col];
        C[off] = val;
      }
    }
  }
}

// ================= in_proj (128x128, K=128): writes hzx(f32) / silu(gate)(f32) =================
__global__ __launch_bounds__(256) void inproj_kernel(const bf16* __restrict__ AH,
                                                     const bf16* __restrict__ AL,
                                                     const bf16* __restrict__ WH,
                                                     const bf16* __restrict__ WL,
                                                     float* __restrict__ hzx,
                                                     float* __restrict__ gate_f) {
  constexpr int BM = 128, BN = 128;
  __shared__ bf16 AsH[BM * 64];
  __shared__ bf16 AsL[BM * 64];
  __shared__ bf16 BsH[BN * 64];
  __shared__ bf16 BsL[BN * 64];
  int tid = threadIdx.x;
  int lane = tid & 63, wid = tid >> 6;
  int wr = wid >> 1, wc = wid & 1;
  int row0 = blockIdx.x * BM, col0 = blockIdx.y * BN;
  int l15 = lane & 15, l4 = lane >> 4;
  f32x4 acc[4][4] = {};
  for (int k0 = 0; k0 < 128; k0 += 64) {
    __syncthreads();
    #pragma unroll
    for (int it = 0; it < 4; ++it) {
      int chunk = it * 256 + tid;
      int r = chunk >> 3;
      int clog = (chunk & 7) ^ (r & 7);
      size_t goff = (size_t)(row0 + r) * 128 + k0 + clog * 8;
      gload_lds16(AH + goff, &AsH[chunk * 8]);
      gload_lds16(AL + goff, &AsL[chunk * 8]);
      size_t woff = (size_t)(col0 + r) * 128 + k0 + clog * 8;
      gload_lds16(WH + woff, &BsH[chunk * 8]);
      gload_lds16(WL + woff, &BsL[chunk * 8]);
    }
    __syncthreads();
    #pragma unroll
    for (int kk = 0; kk < 2; ++kk) {
      bf16x8 afh[4], afl[4], bfh[4], bfl[4];
      #pragma unroll
      for (int u = 0; u < 4; ++u) {
        int r = wr * 64 + u * 16 + l15;
        int csw = (kk * 4 + l4) ^ (r & 7);
        afh[u] = *(const bf16x8*)&AsH[r * 64 + csw * 8];
        afl[u] = *(const bf16x8*)&AsL[r * 64 + csw * 8];
      }
      #pragma unroll
      for (int v = 0; v < 4; ++v) {
        int r = wc * 64 + v * 16 + l15;
        int csw = (kk * 4 + l4) ^ (r & 7);
        bfh[v] = *(const bf16x8*)&BsH[r * 64 + csw * 8];
        bfl[v] = *(const bf16x8*)&BsL[r * 64 + csw * 8];
      }
      #pragma unroll
      for (int u = 0; u < 4; ++u)
        #pragma unroll
        for (int v = 0; v < 4; ++v) {
          acc[u][v] = __builtin_amdgcn_mfma_f32_16x16x32_bf16(afh[u], bfh[v], acc[u][v], 0, 0, 0);
          acc[u][v] = __builtin_amdgcn_mfma_f32_16x16x32_bf16(afl[u], bfh[v], acc[u][v], 0, 0, 0);
          acc[u][v] = __builtin_amdgcn_mfma_f32_16x16x32_bf16(afh[u], bfl[v], acc[u][v], 0, 0, 0);
        }
    }
  }
  bool isgate = (col0 >= 256);
  #pragma unroll
  for (int u = 0; u < 4; ++u) {
    int rbase = row0 + wr * 64 + u * 16 + l4 * 4;
    #pragma unroll
    for (int v = 0; v < 4; ++v) {
      int col = col0 + wc * 64 + v * 16 + l15;
      #pragma unroll
      for (int q = 0; q < 4; ++q) {
        float val = acc[u][v][q];
        if (!isgate) {
          hzx[(size_t)(rbase + q) * 256 + col] = val;
        } else {
          float s = val / (1.0f + __expf(-val));
          gate_f[(size_t)(rbase + q) * 256 + (col - 256)] = s;
        }
      }
    }
  }
}

// ================= x_proj (32x64, K=256) + conv/silu staging + dt + FUSED chunk-scan (phase A) ======
// Block bid covers tokens [bid*32, bid*32+32) == scan chunk (b = bid>>6, c = bid&63).
__global__ __launch_bounds__(256) void xproj_scan_kernel(const float* __restrict__ hzx,
                                                         const float* __restrict__ cw,
                                                         const float* __restrict__ cb,
                                                         const bf16* __restrict__ WH,
                                                         const bf16* __restrict__ WL,
                                                         const float* __restrict__ Wdt,
                                                         const float* __restrict__ bdt,
                                                         const float* __restrict__ A_log,
                                                         __hip_bfloat162* __restrict__ hs_p,
                                                         float* __restrict__ xp,
                                                         float* __restrict__ dtb,
                                                         float* __restrict__ Pb,
                                                         float* __restrict__ Sb) {
  __shared__ bf16 AsH[32 * 64];
  __shared__ bf16 AsL[32 * 64];
  __shared__ bf16 BsH[64 * 64];
  __shared__ bf16 BsL[64 * 64];
  __shared__ float xq[32][24];                 // xp cols 0..23 (dt inputs + B)
  __shared__ __hip_bfloat162 hs_lds[32][257];  // +1 pad: conflict-free
  int tid = threadIdx.x;
  int lane = tid & 63, wid = tid >> 6;
  int wr = wid >> 1, wc = wid & 1;   // wave tile 16x32
  int row0 = blockIdx.x * 32;
  int l15 = lane & 15, l4 = lane >> 4;
  int r = tid >> 3, cslot = tid & 7;
  int tok = row0 + r;
  int lpos = tok & (LSEQ - 1);   // 32 | LSEQ, blocks never straddle sequences
  f32x4 acc[1][2] = {};
  for (int k0 = 0; k0 < 256; k0 += 64) {
    __syncthreads();
    {
      int kb = k0 + ((cslot ^ (r & 7)) << 3);
      const float* hp = &hzx[(size_t)tok * 256 + kb];
      float x3[8], x2[8], x1[8], x0[8];
      *(float4*)&x3[0] = *(const float4*)(hp);
      *(float4*)&x3[4] = *(const float4*)(hp + 4);
      if (lpos >= 1) { *(float4*)&x2[0] = *(const float4*)(hp - 256); *(float4*)&x2[4] = *(const float4*)(hp - 252); }
      else { *(float4*)&x2[0] = make_float4(0,0,0,0); *(float4*)&x2[4] = make_float4(0,0,0,0); }
      if (lpos >= 2) { *(float4*)&x1[0] = *(const float4*)(hp - 512); *(float4*)&x1[4] = *(const float4*)(hp - 508); }
      else { *(float4*)&x1[0] = make_float4(0,0,0,0); *(float4*)&x1[4] = make_float4(0,0,0,0); }
      if (lpos >= 3) { *(float4*)&x0[0] = *(const float4*)(hp - 768); *(float4*)&x0[4] = *(const float4*)(hp - 764); }
      else { *(float4*)&x0[0] = make_float4(0,0,0,0); *(float4*)&x0[4] = make_float4(0,0,0,0); }
      bf16 tH[8], tL[8];
      __hip_bfloat162 pk[8];
      #pragma unroll
      for (int j = 0; j < 8; ++j) {
        float4 w = *(const float4*)&cw[(kb + j) * 4];
        float s = cb[kb + j];
        s = fmaf(x0[j], w.x, s);
        s = fmaf(x1[j], w.y, s);
        s = fmaf(x2[j], w.z, s);
        s = fmaf(x3[j], w.w, s);
        s = s / (1.0f + __expf(-s));
        split_bf16(s, tH[j], tL[j]);
        pk[j].x = tH[j]; pk[j].y = tL[j];
        hs_lds[r][kb + j] = pk[j];
      }
      *(bf16x8*)&AsH[tid * 8] = *(const bf16x8*)tH;
      *(bf16x8*)&AsL[tid * 8] = *(const bf16x8*)tL;
      *(float4*)&hs_p[(size_t)tok * 256 + kb]     = *(const float4*)&pk[0];
      *(float4*)&hs_p[(size_t)tok * 256 + kb + 4] = *(const float4*)&pk[4];
    }
    #pragma unroll
    for (int it = 0; it < 2; ++it) {
      int chunk = it * 256 + tid;
      int rr = chunk >> 3;
      int clog = (chunk & 7) ^ (rr & 7);
      size_t goff = (size_t)rr * 256 + k0 + clog * 8;
      gload_lds16(WH + goff, &BsH[chunk * 8]);
      gload_lds16(WL + goff, &BsL[chunk * 8]);
    }
    __syncthreads();
    #pragma unroll
    for (int kk = 0; kk < 2; ++kk) {
      bf16x8 afh, afl, bfh[2], bfl[2];
      {
        int rr = wr * 16 + l15;
        int csw = (kk * 4 + l4) ^ (rr & 7);
        afh = *(const bf16x8*)&AsH[rr * 64 + csw * 8];
        afl = *(const bf16x8*)&AsL[rr * 64 + csw * 8];
      }
      #pragma unroll
      for (int v = 0; v < 2; ++v) {
        int rr = wc * 32 + v * 16 + l15;
        int csw = (kk * 4 + l4) ^ (rr & 7);
        bfh[v] = *(const bf16x8*)&BsH[rr * 64 + csw * 8];
        bfl[v] = *(const bf16x8*)&BsL[rr * 64 + csw * 8];
      }
      #pragma unroll
      for (int v = 0; v < 2; ++v) {
        acc[0][v] = __builtin_amdgcn_mfma_f32_16x16x32_bf16(afh, bfh[v], acc[0][v], 0, 0, 0);
        acc[0][v] = __builtin_amdgcn_mfma_f32_16x16x32_bf16(afl, bfh[v], acc[0][v], 0, 0, 0);
        acc[0][v] = __builtin_amdgcn_mfma_f32_16x16x32_bf16(afh, bfl[v], acc[0][v], 0, 0, 0);
      }
    }
  }
  // epilogue: write xp; stash cols 0..23 into LDS
  {
    int rbase = wr * 16 + l4 * 4;
    #pragma unroll
    for (int v = 0; v < 2; ++v) {
      int col = wc * 32 + v * 16 + l15;
      #pragma unroll
      for (int q = 0; q < 4; ++q) {
        float val = acc[0][v][q];
        xp[(size_t)(row0 + rbase + q) * 64 + col] = val;
        if (col < 24) xq[rbase + q][col] = val;
      }
    }
  }
  __syncthreads();
  // dt + chunk-scan phase: thread i owns channel i, 16 states in registers
  {
    int i = tid;
    float A[16];
    {
      const float4* ap = (const float4*)&A_log[i * 16];
      #pragma unroll
      for (int q = 0; q < 4; ++q) {
        float4 a = ap[q];
        A[q * 4 + 0] = -__expf(a.x); A[q * 4 + 1] = -__expf(a.y);
        A[q * 4 + 2] = -__expf(a.z); A[q * 4 + 3] = -__expf(a.w);
      }
    }
    const float* wr8 = Wdt + i * 8;
    float w0 = wr8[0], w1 = wr8[1], w2 = wr8[2], w3 = wr8[3];
    float w4 = wr8[4], w5 = wr8[5], w6 = wr8[6], w7 = wr8[7];
    float bv = bdt[i];
    float P[16], S[16];
    #pragma unroll
    for (int n = 0; n < 16; ++n) { P[n] = 1.0f; S[n] = 0.0f; }
    for (int tt = 0; tt < 32; ++tt) {
      const float* q = xq[tt];
      float s = bv;
      s = fmaf(q[0], w0, s); s = fmaf(q[1], w1, s);
      s = fmaf(q[2], w2, s); s = fmaf(q[3], w3, s);
      s = fmaf(q[4], w4, s); s = fmaf(q[5], w5, s);
      s = fmaf(q[6], w6, s); s = fmaf(q[7], w7, s);
      float dtv = (s > 20.0f) ? s : log1pf(__expf(s));
      dtb[(size_t)(row0 + tt) * 256 + i] = dtv;
      __hip_bfloat162 hp = hs_lds[tt][i];
      float hsv = __bfloat162float(hp.x) + __bfloat162float(hp.y);
      float dh = dtv * hsv;
      #pragma unroll
      for (int n = 0; n < 16; ++n) {
        float e = __expf(dtv * A[n]);
        P[n] *= e;
        S[n] = fmaf(S[n], e, dh * q[8 + n]);
      }
    }
    size_t base = ((size_t)blockIdx.x << 12) + i * 16;
    #pragma unroll
    for (int qq = 0; qq < 4; ++qq) {
      *(float4*)&Pb[base + qq * 4] = make_float4(P[qq * 4], P[qq * 4 + 1], P[qq * 4 + 2], P[qq * 4 + 3]);
      *(float4*)&Sb[base + qq * 4] = make_float4(S[qq * 4], S[qq * 4 + 1], S[qq * 4 + 2], S[qq * 4 + 3]);
    }
  }
}

// phase B: sequential prefix over chunks -> initial states. 32768 threads.
__global__ __launch_bounds__(256) void scanB_kernel(const float* __restrict__ Pb,
                                                    const float* __restrict__ Sb,
                                                    float* __restrict__ Ib) {
  int g = blockIdx.x * 256 + threadIdx.x;   // b*4096 + i*16 + n
  int b = g >> 12, rem = g & 4095;
  float s = 0.0f;
  for (int cc = 0; cc < NCH; ++cc) {
    size_t off = ((size_t)(b * NCH + cc) << 12) + rem;
    Ib[off] = s;
    s = fmaf(s, Pb[off], Sb[off]);
  }
}

// ================= out_proj (32x128, K=256) + FUSED scan phase C + residual + next-layer RMSNorm ====
// Block bid covers tokens [bid*32, bid*32+32) == scan chunk; y computed in-kernel into LDS.
__global__ __launch_bounds__(256) void outproj_scan_norm_kernel(const float* __restrict__ dtb,
                                                                const __hip_bfloat162* __restrict__ hs_p,
                                                                const float* __restrict__ xp,
                                                                const float* __restrict__ A_log,
                                                                const float* __restrict__ Dp,
                                                                const float* __restrict__ gate_f,
                                                                const float* __restrict__ Ib,
                                                                const bf16* __restrict__ WH,
                                                                const bf16* __restrict__ WL,
                                                                const float* __restrict__ nw,
                                                                float* __restrict__ Ch,
                                                                bf16* __restrict__ hn_h,
                                                                bf16* __restrict__ hn_l) {
  __shared__ bf16 AsH[32 * 64];
  __shared__ bf16 AsL[32 * 64];
  __shared__ bf16 BsH[128 * 64];
  __shared__ bf16 BsL[128 * 64];
  __shared__ __hip_bfloat162 y_lds[32][257];   // +1 pad
  __shared__ float ssq[32][2];
  int tid = threadIdx.x;
  int lane = tid & 63, wid = tid >> 6;
  int wr = wid >> 1, wc = wid & 1;    // wave tile 16x64
  int row0 = blockIdx.x * 32;
  int l15 = lane & 15, l4 = lane >> 4;
  // ---- phase C: thread i = channel i, replay chunk with initial state from Ib ----
  {
    int i = tid;
    float A[16];
    {
      const float4* ap = (const float4*)&A_log[i * 16];
      #pragma unroll
      for (int q = 0; q < 4; ++q) {
        float4 a = ap[q];
        A[q * 4 + 0] = -__expf(a.x); A[q * 4 + 1] = -__expf(a.y);
        A[q * 4 + 2] = -__expf(a.z); A[q * 4 + 3] = -__expf(a.w);
      }
    }
    float st[16];
    {
      size_t base = ((size_t)blockIdx.x << 12) + i * 16;
      #pragma unroll
      for (int q = 0; q < 4; ++q) {
        float4 s4 = *(const float4*)&Ib[base + q * 4];
        st[q * 4 + 0] = s4.x; st[q * 4 + 1] = s4.y; st[q * 4 + 2] = s4.z; st[q * 4 + 3] = s4.w;
      }
    }
    float Dv = Dp[i];
    for (int tt = 0; tt < 32; ++tt) {
      size_t t = row0 + tt;
      float dtv = dtb[t * 256 + i];
      __hip_bfloat162 hp = hs_p[t * 256 + i];
      float hsv = __bfloat162float(hp.x) + __bfloat162float(hp.y);
      float dh = dtv * hsv;
      float Bv[16], Cv[16];
      #pragma unroll
      for (int q = 0; q < 4; ++q) {
        float4 bv = *(const float4*)&xp[t * 64 + 8 + q * 4];
        Bv[q * 4 + 0] = bv.x; Bv[q * 4 + 1] = bv.y; Bv[q * 4 + 2] = bv.z; Bv[q * 4 + 3] = bv.w;
        float4 cv = *(const float4*)&xp[t * 64 + 24 + q * 4];
        Cv[q * 4 + 0] = cv.x; Cv[q * 4 + 1] = cv.y; Cv[q * 4 + 2] = cv.z; Cv[q * 4 + 3] = cv.w;
      }
      float y0 = 0.f, y1 = 0.f, y2 = 0.f, y3 = 0.f;
      #pragma unroll
      for (int q = 0; q < 4; ++q) {
        float e0 = __expf(dtv * A[q * 4 + 0]);
        float e1 = __expf(dtv * A[q * 4 + 1]);
        float e2 = __expf(dtv * A[q * 4 + 2]);
        float e3 = __expf(dtv * A[q * 4 + 3]);
        st[q * 4 + 0] = fmaf(st[q * 4 + 0], e0, dh * Bv[q * 4 + 0]);
        st[q * 4 + 1] = fmaf(st[q * 4 + 1], e1, dh * Bv[q * 4 + 1]);
        st[q * 4 + 2] = fmaf(st[q * 4 + 2], e2, dh * Bv[q * 4 + 2]);
        st[q * 4 + 3] = fmaf(st[q * 4 + 3], e3, dh * Bv[q * 4 + 3]);
        y0 = fmaf(st[q * 4 + 0], Cv[q * 4 + 0], y0);
        y1 = fmaf(st[q * 4 + 1], Cv[q * 4 + 1], y1);
        y2 = fmaf(st[q * 4 + 2], Cv[q * 4 + 2], y2);
        y3 = fmaf(st[q * 4 + 3], Cv[q * 4 + 3], y3);
      }
      float y = ((y0 + y1) + (y2 + y3)) + hsv * Dv;
      float g = gate_f[t * 256 + i];
      float val = y * g;
      bf16 hh, ll;
      split_bf16(val, hh, ll);
      __hip_bfloat162 pk; pk.x = hh; pk.y = ll;
      y_lds[tt][i] = pk;
    }
  }
  // ---- GEMM: A from y_lds, B from global ----
  f32x4 acc[1][4] = {};
  for (int k0 = 0; k0 < 256; k0 += 64) {
    __syncthreads();
    {
      int chunk = tid;
      int r = chunk >> 3;
      int kb = k0 + (((chunk & 7) ^ (r & 7)) << 3);
      bf16 tH[8], tL[8];
      #pragma unroll
      for (int j = 0; j < 8; ++j) {
        __hip_bfloat162 pk = y_lds[r][kb + j];
        tH[j] = pk.x; tL[j] = pk.y;
      }
      *(bf16x8*)&AsH[tid * 8] = *(const bf16x8*)tH;
      *(bf16x8*)&AsL[tid * 8] = *(const bf16x8*)tL;
    }
    #pragma unroll
    for (int it = 0; it < 4; ++it) {
      int chunk = it * 256 + tid;
      int r = chunk >> 3;
      int clog = (chunk & 7) ^ (r & 7);
      size_t goff = (size_t)r * 256 + k0 + clog * 8;
      gload_lds16(WH + goff, &BsH[chunk * 8]);
      gload_lds16(WL + goff, &BsL[chunk * 8]);
    }
    __syncthreads();
    #pragma unroll
    for (int kk = 0; kk < 2; ++kk) {
      bf16x8 afh, afl, bfh[4], bfl[4];
      {
        int r = wr * 16 + l15;
        int csw = (kk * 4 + l4) ^ (r & 7);
        afh = *(const bf16x8*)&AsH[r * 64 + csw * 8];
        afl = *(const bf16x8*)&AsL[r * 64 + csw * 8];
      }
      #pragma unroll
      for (int v = 0; v < 4; ++v) {
        int r = wc * 64 + v * 16 + l15;
        int csw = (kk * 4 + l4) ^ (r & 7);
        bfh[v] = *(const bf16x8*)&BsH[r * 64 + csw * 8];
        bfl[v] = *(const bf16x8*)&BsL[r * 64 + csw * 8];
      }
      #pragma unroll
      for (int v = 0; v < 4; ++v) {
        acc[0][v] = __builtin_amdgcn_mfma_f32_16x16x32_bf16(afh, bfh[v], acc[0][v], 0, 0, 0);
        acc[0][v] = __builtin_amdgcn_mfma_f32_16x16x32_bf16(afl, bfh[v], acc[0][v], 0, 0, 0);
        acc[0][v] = __builtin_amdgcn_mfma_f32_16x16x32_bf16(afh, bfl[v], acc[0][v], 0, 0, 0);
      }
    }
  }
  int rloc = wr * 16 + l4 * 4;
  float vals[4][4];   // [q][v]
  #pragma unroll
  for (int v = 0; v < 4; ++v) {
    int col = wc * 64 + v * 16 + l15;
    #pragma unroll
    for (int q = 0; q < 4; ++q) {
      size_t off = (size_t)(row0 + rloc + q) * 128 + col;
      float val = acc[0][v][q] + Ch[off];
      vals[q][v] = val;
      Ch[off] = val;
    }
  }
  #pragma unroll
  for (int q = 0; q < 4; ++q) {
    float ss = vals[q][0] * vals[q][0] + vals[q][1] * vals[q][1]
             + vals[q][2] * vals[q][2] + vals[q][3] * vals[q][3];
    ss += __shfl_xor(ss, 1, 16);
    ss += __shfl_xor(ss, 2, 16);
    ss += __shfl_xor(ss, 4, 16);
    ss += __shfl_xor(ss, 8, 16);
    if (l15 == 0) ssq[rloc + q][wc] = ss;
  }
  __syncthreads();
  #pragma unroll
  for (int q = 0; q < 4; ++q) {
    float rstd = rsqrtf((ssq[rloc + q][0] + ssq[rloc + q][1]) * (1.0f / 128.0f) + 1e-5f);
    #pragma unroll
    for (int v = 0; v < 4; ++v) {
      int col = wc * 64 + v * 16 + l15;
      float o = vals[q][v] * rstd * nw[col];
      bf16 hh, ll;
      split_bf16(o, hh, ll);
      size_t off = (size_t)(row0 + rloc + q) * 128 + col;
      hn_h[off] = hh;
      hn_l[off] = ll;
    }
  }
}

extern "C" void kernel_launch(void* const* d_in, const int* in_sizes, int n_in,
                              void* d_out, int out_size, void* d_ws, size_t ws_size,
                              hipStream_t stream) {
  const int* x           = (const int*)d_in[0];
  const float* embed     = (const float*)d_in[1];
  const float* in_proj_w = (const float*)d_in[2];
  const float* conv_w    = (const float*)d_in[3];
  const float* conv_b    = (const float*)d_in[4];
  const float* x_proj_w  = (const float*)d_in[5];
  const float* dt_proj_w = (const float*)d_in[6];
  const float* dt_proj_b = (const float*)d_in[7];
  const float* A_log     = (const float*)d_in[8];
  const float* Dp        = (const float*)d_in[9];
  const float* out_proj_w= (const float*)d_in[10];
  const float* norm_w    = (const float*)d_in[11];
  const float* norm_f_w  = (const float*)d_in[12];
  const float* head_w    = (const float*)d_in[13];
  const float* head_b    = (const float*)d_in[14];

  float* out = (float*)d_out;
  float* ws  = (float*)d_ws;

  // ---- d_out scratch map (f32 word offsets; budget 33,554,432) ----
  float* hzx     = out;                          //  4,194,304 (T*256 f32)
  float* gate_f  = out + 4194304;                //  4,194,304 (T*256 f32)
  __hip_bfloat162* hs_p = (__hip_bfloat162*)(out + 8388608);   // 4,194,304 w (T*256 bf162)
  float* dtb     = out + 12582912;               //  4,194,304 (T*256 f32)
  float* xp      = out + 16777216;               //  1,048,576 (T*64 f32)
  float* Pb      = out + 17825792;               //  2,097,152 (512*4096)
  float* Sb      = out + 19922944;               //  2,097,152
  float* h       = out + 22020096;               //  2,097,152 (T*128 residual)
  bf16*  w_in_h  = (bf16*)(out + 24117248);      //  1,048,576 w
  bf16*  w_in_l  = (bf16*)(out + 25165824);      //  1,048,576 w
  bf16*  w_x_h   = (bf16*)(out + 26214400);      //    262,144 w (padded 64 rows)
  bf16*  w_x_l   = (bf16*)(out + 26476544);
  bf16*  w_out_h = (bf16*)(out + 26738688);      //    524,288 w
  bf16*  w_out_l = (bf16*)(out + 27262976);
  float* Ib      = out + 27787264;               //  2,097,152 -> ends 29,884,416

  // ---- ws scratch (~9.4 MB) — live through the head GEMM ----
  bf16* hn_h     = (bf16*)ws;                    // T*128 bf16
  bf16* hn_l     = (bf16*)(ws + 1048576);
  bf16* w_head_h = (bf16*)(ws + 2097152);        // 2048*128 bf16
  bf16* w_head_l = (bf16*)(ws + 2228224);

  cast_split_kernel<<<8192, 256, 0, stream>>>(in_proj_w, w_in_h, w_in_l, 2097152);
  cast_xproj_kernel<<<2048, 256, 0, stream>>>(x_proj_w, w_x_h, w_x_l);
  cast_split_kernel<<<4096, 256, 0, stream>>>(out_proj_w, w_out_h, w_out_l, 1048576);
  cast_split_kernel<<<1024, 256, 0, stream>>>(head_w, w_head_h, w_head_l, 262144);

  embed_kernel<<<8192, 256, 0, stream>>>(x, embed, h);
  rmsnorm_split_kernel<<<4096, 256, 0, stream>>>(h, norm_w, hn_h, hn_l);

  for (int l = 0; l < 32; ++l) {
    inproj_kernel<<<dim3(128, 4), 256, 0, stream>>>(
        hn_h, hn_l, w_in_h + (size_t)l * 512 * 128, w_in_l + (size_t)l * 512 * 128,
        hzx, gate_f);
    xproj_scan_kernel<<<512, 256, 0, stream>>>(
        hzx, conv_w + l * 1024, conv_b + l * 256,
        w_x_h + (size_t)l * 64 * 256, w_x_l + (size_t)l * 64 * 256,
        dt_proj_w + l * 2048, dt_proj_b + l * 256, A_log + l * 4096,
        hs_p, xp, dtb, Pb, Sb);
    scanB_kernel<<<128, 256, 0, stream>>>(Pb, Sb, Ib);
    const float* nwnext = (l < 31) ? (norm_w + (l + 1) * 128) : norm_f_w;
    outproj_scan_norm_kernel<<<512, 256, 0, stream>>>(
        dtb, hs_p, xp, A_log + l * 4096, Dp + l * 256, gate_f, Ib,
        w_out_h + (size_t)l * 128 * 256, w_out_l + (size_t)l * 128 * 256,
        nwnext, h, hn_h, hn_l);
  }

  mfma_gemm<128, 128, 2, 2, 2><<<dim3(128, 16), 256, 0, stream>>>(
      hn_h, hn_l, w_head_h, w_head_l, out, head_b, 2048, 128);
}